// Round 8
// baseline (481.435 us; speedup 1.0000x reference)
//
#include <hip/hip_runtime.h>
#include <math.h>

// B=2, L=2048, D_MODEL=1024, D_INNER=2048, D_STATE=16, DT_RANK=64, D_CONV=4
// P = B*L = 4096

typedef unsigned short ushort_t;
typedef unsigned int uint_t;
typedef __bf16 bf16x8 __attribute__((ext_vector_type(8)));
typedef float floatx4 __attribute__((ext_vector_type(4)));

#define LDS_STRIDE 40   // 32 + 8 pad shorts

#define GLOAD16(gp, lp) \
    __builtin_amdgcn_global_load_lds((const __attribute__((address_space(1))) void*)(gp), \
                                     (__attribute__((address_space(3))) void*)(lp), 16, 0, 0)

__device__ __forceinline__ float silu_f(float x) { return x / (1.0f + __expf(-x)); }

__device__ __forceinline__ unsigned short f2bf(float f) {
    unsigned u = __float_as_uint(f);
    unsigned r = u + 0x7fffu + ((u >> 16) & 1u);   // RNE (finite values only)
    return (unsigned short)(r >> 16);
}
__device__ __forceinline__ float bf2f(unsigned short h) {
    return __uint_as_float(((unsigned)h) << 16);
}
__device__ __forceinline__ uint_t packhl(float v) {
    const unsigned short h = f2bf(v);
    const unsigned short l = f2bf(v - bf2f(h));
    return (uint_t)h | ((uint_t)l << 16);
}
__device__ __forceinline__ float unpack_sum(uint_t pk) {
    return __uint_as_float(pk << 16) + __uint_as_float(pk & 0xffff0000u);
}
__device__ __forceinline__ void unpack8(uint4 w0, uint4 w1, uint4& H, uint4& L) {
    H.x = (w0.x & 0xffffu) | (w0.y << 16);  L.x = (w0.x >> 16) | (w0.y & 0xffff0000u);
    H.y = (w0.z & 0xffffu) | (w0.w << 16);  L.y = (w0.z >> 16) | (w0.w & 0xffff0000u);
    H.z = (w1.x & 0xffffu) | (w1.y << 16);  L.z = (w1.x >> 16) | (w1.y & 0xffff0000u);
    H.w = (w1.z & 0xffffu) | (w1.w << 16);  L.w = (w1.z >> 16) | (w1.w & 0xffff0000u);
}
// MFMA B-fragment-ordered address for B^T matrix [N][K]:
// lane (m16 + 16*q) of tile (n16, kc) holds B^T[n16*16+m16][kc*32+q*8 .. +8]
__device__ __forceinline__ size_t faddr(int n, int k, int KC) {
    return ((size_t)((n >> 4) * KC + (k >> 5)) * 64 + (n & 15) + (((k >> 3) & 3) << 4)) * 8
           + (k & 7);
}

// ---------------------------------------------------------------------------
// Mega prep kernel (block-range switch). All B-operands written in
// MFMA-fragment order (bf16 hi only).
// ---------------------------------------------------------------------------
__global__ __launch_bounds__(256) void prep_all(
    const float* __restrict__ x, const float* __restrict__ W_in,
    const float* __restrict__ conv_k, const float* __restrict__ W_out,
    const float* __restrict__ W_x,
    uint_t* __restrict__ xpk,
    ushort_t* __restrict__ WinF, ushort_t* __restrict__ convkF,
    ushort_t* __restrict__ WoutF, ushort_t* __restrict__ WxF,
    ushort_t* __restrict__ XSP_h)
{
    __shared__ float ts[32][33];
    const int bid = blockIdx.x;
    const int t = threadIdx.x;
    if (bid < 4096) {
        const size_t i4 = ((size_t)bid * 256 + t) * 4;
        float4 v = *(const float4*)&x[i4];
        uint4 pk;
        pk.x = packhl(v.x); pk.y = packhl(v.y); pk.z = packhl(v.z); pk.w = packhl(v.w);
        *(uint4*)&xpk[i4] = pk;
        return;
    }
    if (bid >= 18432 && bid < 19456) {
        const int idx = (bid - 18432) * 256 + t;
        const int r = idx >> 11, k = idx & 2047;
        float v = (r < 96) ? W_x[(size_t)k * 96 + r] : 0.f;
        WxF[faddr(r, k, 64)] = f2bf(v);
        return;
    }
    if (bid >= 19456) {
        const int idx = (bid - 19456) * 256 + t;   // < 12288
        const int b = idx / 6144, rem = idx % 6144;
        const int lp = rem >> 11, c = rem & 2047;
        XSP_h[((size_t)b * 2051 + lp) * 2048 + c] = 0;
        return;
    }
    // transpose + fragment-order cases (dst is B^T [N=C][K=R])
    const float* src; int R, C, KC; ushort_t* dst; int bx, by;
    if (bid < 8192)       { src = W_in;   R = 1024; C = 4096; KC = 32;  dst = WinF;
                            int l = bid - 4096;  bx = l & 127; by = l >> 7; }
    else if (bid < 16384) { src = conv_k; R = 4096; C = 2048; KC = 128; dst = convkF;
                            int l = bid - 8192;  bx = l & 63;  by = l >> 6; }
    else                  { src = W_out;  R = 2048; C = 1024; KC = 64;  dst = WoutF;
                            int l = bid - 16384; bx = l & 31;  by = l >> 5; }
    const int tx = t & 31, ty = t >> 5;
    const int r0 = by * 32, c0 = bx * 32;
    #pragma unroll
    for (int j = 0; j < 4; ++j)
        ts[ty + j * 8][tx] = src[(size_t)(r0 + ty + j * 8) * C + c0 + tx];
    __syncthreads();
    #pragma unroll
    for (int j = 0; j < 4; ++j) {
        const int n = c0 + ty + j * 8, k = r0 + tx;
        dst[faddr(n, k, KC)] = f2bf(ts[tx][ty + j * 8]);
    }
}

// ---------------------------------------------------------------------------
// 2-term split-bf16 MFMA GEMM, packed A, fragment-ordered direct-global B.
// ---------------------------------------------------------------------------
template<int MODE>
__global__ __launch_bounds__(256) void gemm2(
    const uint_t* __restrict__ Apk, const ushort_t* __restrict__ Bf, int Kfull,
    float* __restrict__ Cf, ushort_t* __restrict__ Oh)
{
    __shared__ __align__(16) ushort_t As_h[128 * LDS_STRIDE];
    __shared__ __align__(16) ushort_t As_l[128 * LDS_STRIDE];
    const int t = threadIdx.x;
    int bx, by;
    if (MODE == 2) { bx = blockIdx.x; by = blockIdx.y; }
    else {
        const int lin = blockIdx.x, xcd = lin & 7, s = lin >> 3;
        bx = s >> 2;
        by = xcd * 4 + (s & 3);
    }
    const int m0 = by * 128;
    const int n0 = (MODE == 2) ? 0 : bx * 128;
    const int kbeg = (MODE == 2) ? bx * 512 : 0;
    const int kend = (MODE == 2) ? kbeg + 512 : Kfull;
    const int KC = Kfull >> 5;
    const int lane = t & 63, wave = t >> 6;
    const int wm = (wave >> 1) * 64, wn = (wave & 1) * 64;
    const int m16 = lane & 15, q = lane >> 4;
    const int n16b = (n0 + wn) >> 4;
    const int r_0 = t >> 2, cc_0 = (t & 3) * 8;
    const int r_1 = (t + 256) >> 2, cc_1 = ((t + 256) & 3) * 8;

    uint4 a00 = *(const uint4*)&Apk[(size_t)(m0 + r_0) * Kfull + kbeg + cc_0];
    uint4 a01 = *(const uint4*)&Apk[(size_t)(m0 + r_0) * Kfull + kbeg + cc_0 + 4];
    uint4 a10 = *(const uint4*)&Apk[(size_t)(m0 + r_1) * Kfull + kbeg + cc_1];
    uint4 a11 = *(const uint4*)&Apk[(size_t)(m0 + r_1) * Kfull + kbeg + cc_1 + 4];
    bf16x8 bc[4];
    {
        const int kc = kbeg >> 5;
        #pragma unroll
        for (int j = 0; j < 4; ++j)
            bc[j] = *(const bf16x8*)&Bf[(((size_t)(n16b + j) * KC + kc) * 64 + lane) * 8];
    }

    floatx4 acc[4][4];
    const floatx4 zz = {0.f, 0.f, 0.f, 0.f};
    #pragma unroll
    for (int i = 0; i < 4; ++i)
        #pragma unroll
        for (int j = 0; j < 4; ++j) acc[i][j] = zz;

    for (int k0 = kbeg; k0 < kend; k0 += 32) {
        uint4 H, L;
        unpack8(a00, a01, H, L);
        *(uint4*)&As_h[r_0 * LDS_STRIDE + cc_0] = H;
        *(uint4*)&As_l[r_0 * LDS_STRIDE + cc_0] = L;
        unpack8(a10, a11, H, L);
        *(uint4*)&As_h[r_1 * LDS_STRIDE + cc_1] = H;
        *(uint4*)&As_l[r_1 * LDS_STRIDE + cc_1] = L;
        __syncthreads();
        bf16x8 bn[4];
        if (k0 + 32 < kend) {
            const int kn = k0 + 32, kc = kn >> 5;
            a00 = *(const uint4*)&Apk[(size_t)(m0 + r_0) * Kfull + kn + cc_0];
            a01 = *(const uint4*)&Apk[(size_t)(m0 + r_0) * Kfull + kn + cc_0 + 4];
            a10 = *(const uint4*)&Apk[(size_t)(m0 + r_1) * Kfull + kn + cc_1];
            a11 = *(const uint4*)&Apk[(size_t)(m0 + r_1) * Kfull + kn + cc_1 + 4];
            #pragma unroll
            for (int j = 0; j < 4; ++j)
                bn[j] = *(const bf16x8*)&Bf[(((size_t)(n16b + j) * KC + kc) * 64 + lane) * 8];
        }
        bf16x8 ah[4], al[4];
        #pragma unroll
        for (int i = 0; i < 4; ++i) {
            const int off = (wm + i * 16 + m16) * LDS_STRIDE + q * 8;
            ah[i] = *(const bf16x8*)&As_h[off];
            al[i] = *(const bf16x8*)&As_l[off];
        }
        #pragma unroll
        for (int i = 0; i < 4; ++i)
            #pragma unroll
            for (int j = 0; j < 4; ++j) {
                acc[i][j] = __builtin_amdgcn_mfma_f32_16x16x32_bf16(ah[i], bc[j], acc[i][j], 0, 0, 0);
                acc[i][j] = __builtin_amdgcn_mfma_f32_16x16x32_bf16(al[i], bc[j], acc[i][j], 0, 0, 0);
            }
        #pragma unroll
        for (int j = 0; j < 4; ++j) bc[j] = bn[j];
        __syncthreads();
    }

    float* Cp = (MODE == 2) ? (Cf + (size_t)bx * 393216) : Cf;
    #pragma unroll
    for (int i = 0; i < 4; ++i) {
        const int row_b = m0 + wm + i * 16 + q * 4;
        #pragma unroll
        for (int j = 0; j < 4; ++j) {
            const int col = n0 + wn + j * 16 + m16;
            #pragma unroll
            for (int rr = 0; rr < 4; ++rr) {
                const int row = row_b + rr;
                const float v = acc[i][j][rr];
                if (MODE == 0) {
                    if (n0 < 2048) {
                        const int b = row >> 11, l = row & 2047;
                        Oh[((size_t)b * 2051 + l + 3) * 2048 + col] = f2bf(v);
                    } else {
                        Cp[(size_t)row * 2048 + (col - 2048)] = v;
                    }
                } else if (MODE == 1) {
                    Cp[(size_t)row * 1024 + col] = v;
                } else {
                    if (col < 96) Cp[(size_t)row * 96 + col] = v;
                }
            }
        }
    }
}

// ---------------------------------------------------------------------------
// Conv as MFMA GEMM — r7 schedule at 256x128 tile (LDS-traffic reduction).
// r7 (128x128, 16 waves/CU) measured EXACTLY its LDS-BW floor:
//   reads 96KB + writes 32KB per CU per 32-K = 1505 cy x 128 = 80 µs.
// 256x128 with 8 waves of 64x64 cuts read redundancy:
//   reads 8x(64+64)x32x2 = 64KB + writes 24KB = 88KB -> floor 55 µs.
// Grid 16x16 = 256 blocks = 1/CU (full chip). LDS 96 KiB, 2 waves/SIMD —
// latency covered by the same read-ahead + counted-vmcnt(3) skeleton.
// XCD map: by=(xcd>>2)*8+(s&7), bx=(xcd&3)*4+(s>>3) — A 4MB / B 4MB per XCD.
// Epilogue: u = silu(acc+bias) -> Upk (packed hi|lo).
// ---------------------------------------------------------------------------
__global__ __launch_bounds__(512, 2) void conv2(
    const ushort_t* __restrict__ Xh, const ushort_t* __restrict__ Bf,
    const float* __restrict__ bias, uint_t* __restrict__ Upk)
{
    __shared__ __align__(16) ushort_t Asw[2][2][256 * 32];   // 64 KiB
    __shared__ __align__(16) ushort_t Bsw[2][2][8 * 512];    // 32 KiB
    const int t = threadIdx.x;
    const int lin = blockIdx.x, xcd = lin & 7, s = lin >> 3;   // s in [0,32)
    const int by = (xcd >> 2) * 8 + (s & 7);     // 16 values
    const int bx = (xcd & 3) * 4 + (s >> 3);     // 16 values
    const int m0 = by * 256, n0 = bx * 128;
    const int g1024 = (n0 >= 1024) ? 1024 : 0;
    const int lane = t & 63, wave = t >> 6;          // wave 0..7
    const int wm = (wave >> 1) * 64, wn = (wave & 1) * 64;   // 4M x 2N wave grid
    const int m16 = lane & 15, q = lane >> 4;
    const int n16base = n0 >> 4;
    const int Xrow0 = (m0 >> 11) * 2051 + (m0 & 2047);   // b*2051 + l-base
    // staging lane geometry for A: 1KB issue = 16 rows x 4 chunks(16B)
    const int l16 = lane >> 2;                        // row within 16
    const int csA = (lane & 3) ^ ((lane >> 3) & 3);   // inverse-swizzled src chunk

    // stage kc-half kcL of tile Tn: 2 A-issues + 1 B-issue per wave (3 total)
    auto stageT = [&](int dbuf, int kcL, int Tn) {
        const int wtap = Tn >> 4;                     // conv tap, const per tile
        const int i0 = ((Tn << 6) & 1023) + kcL * 32; // k-col within tap group
        const int kc = Tn * 2 + kcL;
        #pragma unroll
        for (int ii = 0; ii < 2; ++ii) {
            const int r0 = wave * 32 + ii * 16;       // wave-uniform row base
            const size_t gidx = (size_t)(Xrow0 + r0 + l16 + wtap) * 2048
                              + g1024 + i0 + csA * 8;
            GLOAD16(Xh + gidx, &Asw[dbuf][kcL][r0 * 32]);
        }
        const size_t gidx = ((size_t)(n16base + wave) * 128 + kc) * 512 + lane * 8;
        GLOAD16(Bf + gidx, &Bsw[dbuf][kcL][wave * 512]);
    };

    floatx4 acc[4][4];
    const floatx4 zz = {0.f, 0.f, 0.f, 0.f};
    #pragma unroll
    for (int i = 0; i < 4; ++i)
        #pragma unroll
        for (int j = 0; j < 4; ++j) acc[i][j] = zz;

    bf16x8 a0[4], b0[4], a1[4], b1[4];

    auto readA = [&](int dbuf, int kcL, bf16x8 (&ah)[4]) {
        #pragma unroll
        for (int mi = 0; mi < 4; ++mi) {
            const int rr2 = wm + mi * 16 + m16;
            const int ch = q ^ ((m16 >> 1) & 3);      // swizzled chunk
            ah[mi] = *(const bf16x8*)&Asw[dbuf][kcL][rr2 * 32 + ch * 8];
        }
    };
    auto readB = [&](int dbuf, int kcL, bf16x8 (&bb)[4]) {
        #pragma unroll
        for (int j = 0; j < 4; ++j)
            bb[j] = *(const bf16x8*)&Bsw[dbuf][kcL][((wn >> 4) + j) * 512 + lane * 8];
    };
    auto mfma16 = [&](bf16x8 (&ah)[4], bf16x8 (&bb)[4]) {
        __builtin_amdgcn_s_setprio(1);
        #pragma unroll
        for (int mi = 0; mi < 4; ++mi)
            #pragma unroll
            for (int j = 0; j < 4; ++j)
                acc[mi][j] = __builtin_amdgcn_mfma_f32_16x16x32_bf16(ah[mi], bb[j], acc[mi][j], 0, 0, 0);
        __builtin_amdgcn_s_setprio(0);
    };

    // prologue: stage tile 0 (both halves, 3+3 loads), wait kc0, preload regs
    stageT(0, 0, 0);
    stageT(0, 1, 0);
    asm volatile("s_waitcnt vmcnt(3)" ::: "memory");
    __builtin_amdgcn_s_barrier();
    asm volatile("" ::: "memory");
    readA(0, 0, a0); readB(0, 0, b0);

    int cur = 0;
    for (int T = 0; T < 64; ++T) {
        const int nxt = cur ^ 1;
        if (T < 63) {
            stageT(nxt, 0, T + 1);                       // +3 (T+1,kc0)
            asm volatile("s_waitcnt vmcnt(3)" ::: "memory");   // (T,kc1) landed
        } else {
            asm volatile("s_waitcnt vmcnt(0)" ::: "memory");
        }
        __builtin_amdgcn_s_barrier();                    // (T,kc1) visible
        asm volatile("" ::: "memory");
        readA(cur, 1, a1); readB(cur, 1, b1);            // fly under next MFMA
        mfma16(a0, b0);                                  // consume (T,kc0)
        if (T < 63) stageT(nxt, 1, T + 1);               // +3 (T+1,kc1)
        mfma16(a1, b1);                                  // consume (T,kc1)
        asm volatile("" ::: "memory");
        if (T < 63) {
            asm volatile("s_waitcnt vmcnt(3)" ::: "memory");   // (T+1,kc0) landed
            __builtin_amdgcn_s_barrier();                // visible; all reads of
            asm volatile("" ::: "memory");               // buf[cur] consumed above
            readA(nxt, 0, a0); readB(nxt, 0, b0);        // fly under next iter
        }
        cur = nxt;
    }

    #pragma unroll
    for (int i = 0; i < 4; ++i) {
        const int row_b = m0 + wm + i * 16 + q * 4;
        #pragma unroll
        for (int j = 0; j < 4; ++j) {
            const int col = n0 + wn + j * 16 + m16;
            const float bz = bias[col];
            #pragma unroll
            for (int rr = 0; rr < 4; ++rr) {
                const int row = row_b + rr;
                const float v = silu_f(acc[i][j][rr] + bz);
                Upk[(size_t)row * 2048 + col] = packhl(v);
            }
        }
    }
}

// Sum the 4 split-K partials of dbc.
__global__ __launch_bounds__(256) void dbc_reduce(
    const float* __restrict__ DBCP, float* __restrict__ DBC)
{
    const int i = blockIdx.x * 256 + threadIdx.x;   // < 393216
    DBC[i] = (DBCP[i] + DBCP[393216 + i]) + (DBCP[786432 + i] + DBCP[1179648 + i]);
}

// ---------------------------------------------------------------------------
// delta[p,d] = clip(softplus(dbc[p,0:64] @ W_dt[:,d] + b_dt[d]), 1e-3, 1e-1)
// ---------------------------------------------------------------------------
__global__ __launch_bounds__(256) void delta_kernel(
    const float* __restrict__ DBC, const float* __restrict__ W_dt,
    const float* __restrict__ b_dt, float* __restrict__ DELTA)
{
    const int n  = blockIdx.x * 256 + threadIdx.x;
    const int p0 = blockIdx.y * 16;
    const int t  = threadIdx.x;
    __shared__ float dt_s[16][64];
    #pragma unroll
    for (int j = 0; j < 4; ++j) {
        const int lin = j * 256 + t;
        const int r = lin >> 6, k = lin & 63;
        dt_s[r][k] = DBC[(size_t)(p0 + r) * 96 + k];
    }
    __syncthreads();
    float acc[16];
    const float bz = b_dt[n];
    #pragma unroll
    for (int r = 0; r < 16; ++r) acc[r] = bz;
    for (int k = 0; k < 64; ++k) {
        const float wv = W_dt[(size_t)k * 2048 + n];
        #pragma unroll
        for (int r = 0; r < 16; ++r) acc[r] += dt_s[r][k] * wv;
    }
    #pragma unroll
    for (int r = 0; r < 16; ++r) {
        float a = acc[r];
        float sp = (a > 20.f) ? a : log1pf(expf(a));
        sp = fminf(fmaxf(sp, 0.001f), 0.1f);
        DELTA[(size_t)(p0 + r) * 2048 + n] = sp;
    }
}

// ---------------------------------------------------------------------------
// Chunked scan (64 chunks of 32). HEND/HINIT [c][b][d][16n]; SD[c][b][d].
// ---------------------------------------------------------------------------
__global__ __launch_bounds__(256) void scan_p1(
    const float* __restrict__ DELTA, const uint_t* __restrict__ Upk,
    const float* __restrict__ DBC, const float* __restrict__ A_log,
    float* __restrict__ HEND, float* __restrict__ SD)
{
    const int t = threadIdx.x;
    const int d = blockIdx.x * 256 + t;
    const int c = blockIdx.y;
    const int b = blockIdx.z;
    const int p0 = b * 2048 + c * 32;
    __shared__ float Bs[32][16];
    for (int lin = t; lin < 512; lin += 256) {
        const int s = lin >> 4, n = lin & 15;
        Bs[s][n] = DBC[(size_t)(p0 + s) * 96 + 64 + n];
    }
    __syncthreads();
    float Af[16];
    *(float4*)&Af[0]  = *(const float4*)&A_log[(size_t)d * 16 + 0];
    *(float4*)&Af[4]  = *(const float4*)&A_log[(size_t)d * 16 + 4];
    *(float4*)&Af[8]  = *(const float4*)&A_log[(size_t)d * 16 + 8];
    *(float4*)&Af[12] = *(const float4*)&A_log[(size_t)d * 16 + 12];
    #pragma unroll
    for (int n = 0; n < 16; ++n) Af[n] = -__expf(Af[n]);

    float h[16] = {};
    float sd = 0.f;
    for (int s = 0; s < 32; ++s) {
        const size_t ix = (size_t)(p0 + s) * 2048 + d;
        const float dv = DELTA[ix];
        const float uv = unpack_sum(Upk[ix]);
        const float du = dv * uv;
        sd += dv;
        #pragma unroll
        for (int n = 0; n < 16; ++n)
            h[n] = __expf(dv * Af[n]) * h[n] + du * Bs[s][n];
    }
    const size_t hb = (((size_t)c * 2 + b) * 2048 + d) * 16;
    *(float4*)&HEND[hb + 0]  = *(float4*)&h[0];
    *(float4*)&HEND[hb + 4]  = *(float4*)&h[4];
    *(float4*)&HEND[hb + 8]  = *(float4*)&h[8];
    *(float4*)&HEND[hb + 12] = *(float4*)&h[12];
    SD[((size_t)c * 2 + b) * 2048 + d] = sd;
}

__global__ __launch_bounds__(256) void scan_p2(
    const float* __restrict__ HEND, const float* __restrict__ SD,
    const float* __restrict__ A_log, float* __restrict__ HINIT)
{
    const int g = blockIdx.x * 256 + threadIdx.x;   // < 65536
    const int n = g & 15, d = (g >> 4) & 2047, b = (g >> 15) & 1;
    const float Af = -__expf(A_log[(size_t)d * 16 + n]);
    float h = 0.f;
    #pragma unroll 8
    for (int c = 0; c < 64; ++c) {
        const size_t cb = (size_t)c * 2 + b;
        const size_t idx = (cb * 2048 + d) * 16 + n;
        HINIT[idx] = h;
        h = __expf(Af * SD[cb * 2048 + d]) * h + HEND[idx];
    }
}

// Pass 3: re-scan from h_init, y, gate; emit G packed hi|lo.
__global__ __launch_bounds__(256) void scan_p3(
    const float* __restrict__ DELTA, const uint_t* __restrict__ Upk,
    const float* __restrict__ DBC, const float* __restrict__ RES,
    const float* __restrict__ A_log, const float* __restrict__ Dp,
    const float* __restrict__ HINIT, uint_t* __restrict__ Gpk)
{
    const int t = threadIdx.x;
    const int d = blockIdx.x * 256 + t;
    const int c = blockIdx.y;
    const int b = blockIdx.z;
    const int p0 = b * 2048 + c * 32;
    __shared__ float Bs[32][16];
    __shared__ float Cs[32][16];
    for (int lin = t; lin < 512; lin += 256) {
        const int s = lin >> 4, n = lin & 15;
        Bs[s][n] = DBC[(size_t)(p0 + s) * 96 + 64 + n];
        Cs[s][n] = DBC[(size_t)(p0 + s) * 96 + 80 + n];
    }
    __syncthreads();
    float Af[16];
    *(float4*)&Af[0]  = *(const float4*)&A_log[(size_t)d * 16 + 0];
    *(float4*)&Af[4]  = *(const float4*)&A_log[(size_t)d * 16 + 4];
    *(float4*)&Af[8]  = *(const float4*)&A_log[(size_t)d * 16 + 8];
    *(float4*)&Af[12] = *(const float4*)&A_log[(size_t)d * 16 + 12];
    #pragma unroll
    for (int n = 0; n < 16; ++n) Af[n] = -__expf(Af[n]);

    const size_t hb = (((size_t)c * 2 + b) * 2048 + d) * 16;
    float h[16];
    *(float4*)&h[0]  = *(const float4*)&HINIT[hb + 0];
    *(float4*)&h[4]  = *(const float4*)&HINIT[hb + 4];
    *(float4*)&h[8]  = *(const float4*)&HINIT[hb + 8];
    *(float4*)&h[12] = *(const float4*)&HINIT[hb + 12];
    const float Dd = Dp[d];

    for (int s = 0; s < 32; ++s) {
        const int p = p0 + s;
        const size_t ix = (size_t)p * 2048 + d;
        const float dv = DELTA[ix];
        const float uv = unpack_sum(Upk[ix]);
        const float du = dv * uv;
        float y = 0.f;
        #pragma unroll
        for (int n = 0; n < 16; ++n) {
            h[n] = __expf(dv * Af[n]) * h[n] + du * Bs[s][n];
            y += h[n] * Cs[s][n];
        }
        const float resv = RES[ix];
        const float gv = (y + uv * Dd) * silu_f(resv);
        Gpk[ix] = packhl(gv);
    }
}

// ---------------------------------------------------------------------------
extern "C" void kernel_launch(void* const* d_in, const int* in_sizes, int n_in,
                              void* d_out, int out_size, void* d_ws, size_t ws_size,
                              hipStream_t stream) {
    const float* x      = (const float*)d_in[0];
    const float* W_in   = (const float*)d_in[1];
    const float* conv_k = (const float*)d_in[2];
    const float* conv_b = (const float*)d_in[3];
    const float* W_x    = (const float*)d_in[4];
    const float* W_dt   = (const float*)d_in[5];
    const float* b_dt   = (const float*)d_in[6];
    const float* A_log  = (const float*)d_in[7];
    const float* Dv     = (const float*)d_in[8];
    const float* W_out  = (const float*)d_in[9];
    float* out = (float*)d_out;

    char* base = (char*)d_ws;
    float*    RES      = (float*)(base);                  // 33,554,432
    uint_t*   Upk      = (uint_t*)(base + 33554432);      // 33,554,432
    float*    DELTA    = (float*)(base + 67108864);       // 33,554,432
    ushort_t* XSP_h    = (ushort_t*)(base + 100663296);   // 16,801,792 (2 x 2051 x 2048)
    float*    HEND     = (float*)(base + 100663296);      // alias over XSP (dead after conv2)
    uint_t*   xpk      = (uint_t*)(base + 117465088);     // 16,777,216
    ushort_t* convkF   = (ushort_t*)(base + 134242304);   // 16,777,216
    uint_t*   Gpk      = (uint_t*)(base + 117465088);     // alias over xpk+convkF (dead)
    ushort_t* WinF     = (ushort_t*)(base + 151019520);   //  8,388,608
    ushort_t* WoutF    = (ushort_t*)(base + 159408128);   //  4,194,304
    ushort_t* WxF      = (ushort_t*)(base + 163602432);   //    524,288
    float*    DBCP     = (float*)(base + 164126720);      //  6,291,456
    float*    DBC      = (float*)(base + 170418176);      //  1,572,864
    float*    SD       = (float*)(base + 171991040);      //  1,048,576
    float*    HINIT    = (float*)(base + 173039616);      // 16,777,216

    // 0) all prep in one launch
    prep_all<<<19504, 256, 0, stream>>>(x, W_in, conv_k, W_out, W_x,
                                        xpk, WinF, convkF, WoutF, WxF, XSP_h);
    // 1) xz: xs -> XSP bf16 hi (+pad), res -> RES fp32
    gemm2<0><<<1024, 256, 0, stream>>>(xpk, WinF, 1024, RES, XSP_h);
    // 2) u = silu(conv + b) -> Upk (256x128 tile, r7 schedule, 1 block/CU)
    conv2<<<256, 512, 0, stream>>>(XSP_h, convkF, conv_b, Upk);
    // 3) dbc = U @ W_x, split-K x4 + reduce
    gemm2<2><<<dim3(4, 32), 256, 0, stream>>>(Upk, WxF, 2048, DBCP, nullptr);
    dbc_reduce<<<1536, 256, 0, stream>>>(DBCP, DBC);
    // 4) delta
    delta_kernel<<<dim3(8, 256), 256, 0, stream>>>(DBC, W_dt, b_dt, DELTA);
    // 5) chunked scan
    scan_p1<<<dim3(8, 64, 2), 256, 0, stream>>>(DELTA, Upk, DBC, A_log, HEND, SD);
    scan_p2<<<256, 256, 0, stream>>>(HEND, SD, A_log, HINIT);
    scan_p3<<<dim3(8, 64, 2), 256, 0, stream>>>(DELTA, Upk, DBC, RES, A_log, Dv,
                                                HINIT, Gpk);
    // 6) out = G @ W_out
    gemm2<1><<<256, 256, 0, stream>>>(Gpk, WoutF, 2048, out, nullptr);
}

// Round 9
// 473.783 us; speedup vs baseline: 1.0162x; 1.0162x over previous
//
#include <hip/hip_runtime.h>
#include <math.h>

// B=2, L=2048, D_MODEL=1024, D_INNER=2048, D_STATE=16, DT_RANK=64, D_CONV=4
// P = B*L = 4096

typedef unsigned short ushort_t;
typedef unsigned int uint_t;
typedef __bf16 bf16x8 __attribute__((ext_vector_type(8)));
typedef float floatx4 __attribute__((ext_vector_type(4)));

#define LDS_STRIDE 40   // 32 + 8 pad shorts

#define GLOAD16(gp, lp) \
    __builtin_amdgcn_global_load_lds((const __attribute__((address_space(1))) void*)(gp), \
                                     (__attribute__((address_space(3))) void*)(lp), 16, 0, 0)

__device__ __forceinline__ float silu_f(float x) { return x / (1.0f + __expf(-x)); }

__device__ __forceinline__ unsigned short f2bf(float f) {
    unsigned u = __float_as_uint(f);
    unsigned r = u + 0x7fffu + ((u >> 16) & 1u);   // RNE (finite values only)
    return (unsigned short)(r >> 16);
}
__device__ __forceinline__ float bf2f(unsigned short h) {
    return __uint_as_float(((unsigned)h) << 16);
}
__device__ __forceinline__ uint_t packhl(float v) {
    const unsigned short h = f2bf(v);
    const unsigned short l = f2bf(v - bf2f(h));
    return (uint_t)h | ((uint_t)l << 16);
}
__device__ __forceinline__ float unpack_sum(uint_t pk) {
    return __uint_as_float(pk << 16) + __uint_as_float(pk & 0xffff0000u);
}
__device__ __forceinline__ void unpack8(uint4 w0, uint4 w1, uint4& H, uint4& L) {
    H.x = (w0.x & 0xffffu) | (w0.y << 16);  L.x = (w0.x >> 16) | (w0.y & 0xffff0000u);
    H.y = (w0.z & 0xffffu) | (w0.w << 16);  L.y = (w0.z >> 16) | (w0.w & 0xffff0000u);
    H.z = (w1.x & 0xffffu) | (w1.y << 16);  L.z = (w1.x >> 16) | (w1.y & 0xffff0000u);
    H.w = (w1.z & 0xffffu) | (w1.w << 16);  L.w = (w1.z >> 16) | (w1.w & 0xffff0000u);
}
// MFMA B-fragment-ordered address for B^T matrix [N][K]:
// lane (m16 + 16*q) of tile (n16, kc) holds B^T[n16*16+m16][kc*32+q*8 .. +8]
__device__ __forceinline__ size_t faddr(int n, int k, int KC) {
    return ((size_t)((n >> 4) * KC + (k >> 5)) * 64 + (n & 15) + (((k >> 3) & 3) << 4)) * 8
           + (k & 7);
}

// ---------------------------------------------------------------------------
// Mega prep kernel (block-range switch). All B-operands written in
// MFMA-fragment order (bf16 hi only). x is now split into TWO bf16 planes
// (xh = hi, xl = lo residual) so gemm0p can stage both via global_load_lds.
// ---------------------------------------------------------------------------
__global__ __launch_bounds__(256) void prep_all(
    const float* __restrict__ x, const float* __restrict__ W_in,
    const float* __restrict__ conv_k, const float* __restrict__ W_out,
    const float* __restrict__ W_x,
    ushort_t* __restrict__ xh, ushort_t* __restrict__ xl,
    ushort_t* __restrict__ WinF, ushort_t* __restrict__ convkF,
    ushort_t* __restrict__ WoutF, ushort_t* __restrict__ WxF,
    ushort_t* __restrict__ XSP_h)
{
    __shared__ float ts[32][33];
    const int bid = blockIdx.x;
    const int t = threadIdx.x;
    if (bid < 4096) {
        const size_t i4 = ((size_t)bid * 256 + t) * 4;
        float4 v = *(const float4*)&x[i4];
        ushort4 h, l;
        h.x = f2bf(v.x); l.x = f2bf(v.x - bf2f(h.x));
        h.y = f2bf(v.y); l.y = f2bf(v.y - bf2f(h.y));
        h.z = f2bf(v.z); l.z = f2bf(v.z - bf2f(h.z));
        h.w = f2bf(v.w); l.w = f2bf(v.w - bf2f(h.w));
        *(ushort4*)&xh[i4] = h;
        *(ushort4*)&xl[i4] = l;
        return;
    }
    if (bid >= 18432 && bid < 19456) {
        const int idx = (bid - 18432) * 256 + t;
        const int r = idx >> 11, k = idx & 2047;
        float v = (r < 96) ? W_x[(size_t)k * 96 + r] : 0.f;
        WxF[faddr(r, k, 64)] = f2bf(v);
        return;
    }
    if (bid >= 19456) {
        const int idx = (bid - 19456) * 256 + t;   // < 12288
        const int b = idx / 6144, rem = idx % 6144;
        const int lp = rem >> 11, c = rem & 2047;
        XSP_h[((size_t)b * 2051 + lp) * 2048 + c] = 0;
        return;
    }
    // transpose + fragment-order cases (dst is B^T [N=C][K=R])
    const float* src; int R, C, KC; ushort_t* dst; int bx, by;
    if (bid < 8192)       { src = W_in;   R = 1024; C = 4096; KC = 32;  dst = WinF;
                            int l = bid - 4096;  bx = l & 127; by = l >> 7; }
    else if (bid < 16384) { src = conv_k; R = 4096; C = 2048; KC = 128; dst = convkF;
                            int l = bid - 8192;  bx = l & 63;  by = l >> 6; }
    else                  { src = W_out;  R = 2048; C = 1024; KC = 64;  dst = WoutF;
                            int l = bid - 16384; bx = l & 31;  by = l >> 5; }
    const int tx = t & 31, ty = t >> 5;
    const int r0 = by * 32, c0 = bx * 32;
    #pragma unroll
    for (int j = 0; j < 4; ++j)
        ts[ty + j * 8][tx] = src[(size_t)(r0 + ty + j * 8) * C + c0 + tx];
    __syncthreads();
    #pragma unroll
    for (int j = 0; j < 4; ++j) {
        const int n = c0 + ty + j * 8, k = r0 + tx;
        dst[faddr(n, k, KC)] = f2bf(ts[tx][ty + j * 8]);
    }
}

// ---------------------------------------------------------------------------
// 2-term split-bf16 MFMA GEMM, packed A, fragment-ordered direct-global B.
// (Used for MODE 1 (out) and MODE 2 (dbc split-K) only; MODE 0 replaced by
// gemm0p below.)
// ---------------------------------------------------------------------------
template<int MODE>
__global__ __launch_bounds__(256) void gemm2(
    const uint_t* __restrict__ Apk, const ushort_t* __restrict__ Bf, int Kfull,
    float* __restrict__ Cf, ushort_t* __restrict__ Oh)
{
    __shared__ __align__(16) ushort_t As_h[128 * LDS_STRIDE];
    __shared__ __align__(16) ushort_t As_l[128 * LDS_STRIDE];
    const int t = threadIdx.x;
    int bx, by;
    if (MODE == 2) { bx = blockIdx.x; by = blockIdx.y; }
    else {
        const int lin = blockIdx.x, xcd = lin & 7, s = lin >> 3;
        bx = s >> 2;
        by = xcd * 4 + (s & 3);
    }
    const int m0 = by * 128;
    const int n0 = (MODE == 2) ? 0 : bx * 128;
    const int kbeg = (MODE == 2) ? bx * 512 : 0;
    const int kend = (MODE == 2) ? kbeg + 512 : Kfull;
    const int KC = Kfull >> 5;
    const int lane = t & 63, wave = t >> 6;
    const int wm = (wave >> 1) * 64, wn = (wave & 1) * 64;
    const int m16 = lane & 15, q = lane >> 4;
    const int n16b = (n0 + wn) >> 4;
    const int r_0 = t >> 2, cc_0 = (t & 3) * 8;
    const int r_1 = (t + 256) >> 2, cc_1 = ((t + 256) & 3) * 8;

    uint4 a00 = *(const uint4*)&Apk[(size_t)(m0 + r_0) * Kfull + kbeg + cc_0];
    uint4 a01 = *(const uint4*)&Apk[(size_t)(m0 + r_0) * Kfull + kbeg + cc_0 + 4];
    uint4 a10 = *(const uint4*)&Apk[(size_t)(m0 + r_1) * Kfull + kbeg + cc_1];
    uint4 a11 = *(const uint4*)&Apk[(size_t)(m0 + r_1) * Kfull + kbeg + cc_1 + 4];
    bf16x8 bc[4];
    {
        const int kc = kbeg >> 5;
        #pragma unroll
        for (int j = 0; j < 4; ++j)
            bc[j] = *(const bf16x8*)&Bf[(((size_t)(n16b + j) * KC + kc) * 64 + lane) * 8];
    }

    floatx4 acc[4][4];
    const floatx4 zz = {0.f, 0.f, 0.f, 0.f};
    #pragma unroll
    for (int i = 0; i < 4; ++i)
        #pragma unroll
        for (int j = 0; j < 4; ++j) acc[i][j] = zz;

    for (int k0 = kbeg; k0 < kend; k0 += 32) {
        uint4 H, L;
        unpack8(a00, a01, H, L);
        *(uint4*)&As_h[r_0 * LDS_STRIDE + cc_0] = H;
        *(uint4*)&As_l[r_0 * LDS_STRIDE + cc_0] = L;
        unpack8(a10, a11, H, L);
        *(uint4*)&As_h[r_1 * LDS_STRIDE + cc_1] = H;
        *(uint4*)&As_l[r_1 * LDS_STRIDE + cc_1] = L;
        __syncthreads();
        bf16x8 bn[4];
        if (k0 + 32 < kend) {
            const int kn = k0 + 32, kc = kn >> 5;
            a00 = *(const uint4*)&Apk[(size_t)(m0 + r_0) * Kfull + kn + cc_0];
            a01 = *(const uint4*)&Apk[(size_t)(m0 + r_0) * Kfull + kn + cc_0 + 4];
            a10 = *(const uint4*)&Apk[(size_t)(m0 + r_1) * Kfull + kn + cc_1];
            a11 = *(const uint4*)&Apk[(size_t)(m0 + r_1) * Kfull + kn + cc_1 + 4];
            #pragma unroll
            for (int j = 0; j < 4; ++j)
                bn[j] = *(const bf16x8*)&Bf[(((size_t)(n16b + j) * KC + kc) * 64 + lane) * 8];
        }
        bf16x8 ah[4], al[4];
        #pragma unroll
        for (int i = 0; i < 4; ++i) {
            const int off = (wm + i * 16 + m16) * LDS_STRIDE + q * 8;
            ah[i] = *(const bf16x8*)&As_h[off];
            al[i] = *(const bf16x8*)&As_l[off];
        }
        #pragma unroll
        for (int i = 0; i < 4; ++i)
            #pragma unroll
            for (int j = 0; j < 4; ++j) {
                acc[i][j] = __builtin_amdgcn_mfma_f32_16x16x32_bf16(ah[i], bc[j], acc[i][j], 0, 0, 0);
                acc[i][j] = __builtin_amdgcn_mfma_f32_16x16x32_bf16(al[i], bc[j], acc[i][j], 0, 0, 0);
            }
        #pragma unroll
        for (int j = 0; j < 4; ++j) bc[j] = bn[j];
        __syncthreads();
    }

    float* Cp = (MODE == 2) ? (Cf + (size_t)bx * 393216) : Cf;
    #pragma unroll
    for (int i = 0; i < 4; ++i) {
        const int row_b = m0 + wm + i * 16 + q * 4;
        #pragma unroll
        for (int j = 0; j < 4; ++j) {
            const int col = n0 + wn + j * 16 + m16;
            #pragma unroll
            for (int rr = 0; rr < 4; ++rr) {
                const int row = row_b + rr;
                const float v = acc[i][j][rr];
                if (MODE == 1) {
                    Cp[(size_t)row * 1024 + col] = v;
                } else {
                    if (col < 96) Cp[(size_t)row * 96 + col] = v;
                }
            }
        }
    }
}

// ---------------------------------------------------------------------------
// gemm0p: xz GEMM (4096x4096x1024, 2-term split-bf16) with the conv2-verified
// pipelined structure. A is pre-split into xh/xl bf16 planes so ALL staging
// is global_load_lds (no unpack VALU, no reg round-trip):
//   - 128x128 tile, 8 waves of 64x32, BK=32 single-phase double-buffer.
//   - Per K-step per wave: 3 gload_lds (Ah, Al, B) -> counted vmcnt(3);
//     2 barriers/step; 16 MFMA (8 hi + 8 lo) per wave.
//   - LDS 48 KiB -> >=2 blocks/CU (>=4 waves/SIMD, the proven TLP regime).
//   - XCD map: by=(xcd>>1)*8+(s&7), bx=(xcd&1)*16+(s>>3): A 4MB + B 4MB /XCD.
//   - A chunk swizzle as conv2: src chunk (lane&3)^((lane>>3)&3), read chunk
//     q^((m16>>1)&3).
// Epilogue MODE-0 semantics: cols<2048 -> XSP_h bf16 (+3-row causal pad);
// cols>=2048 -> RES fp32.
// ---------------------------------------------------------------------------
__global__ __launch_bounds__(512, 4) void gemm0p(
    const ushort_t* __restrict__ Ahp, const ushort_t* __restrict__ Alp,
    const ushort_t* __restrict__ Bf,
    float* __restrict__ RES, ushort_t* __restrict__ XSP)
{
    __shared__ __align__(16) ushort_t AhS[2][128 * 32];   // 16 KiB
    __shared__ __align__(16) ushort_t AlS[2][128 * 32];   // 16 KiB
    __shared__ __align__(16) ushort_t BS[2][8 * 512];     // 16 KiB
    const int t = threadIdx.x;
    const int lin = blockIdx.x, xcd = lin & 7, s = lin >> 3;   // s in [0,128)
    const int by = (xcd >> 1) * 8 + (s & 7);     // [0,32)
    const int bx = (xcd & 1) * 16 + (s >> 3);    // [0,32)
    const int m0 = by * 128, n0 = bx * 128;
    const int lane = t & 63, wave = t >> 6;          // wave 0..7
    const int wm = (wave >> 2) * 64, wn = (wave & 3) * 32;
    const int m16 = lane & 15, q = lane >> 4;
    const int n16base = n0 >> 4;
    const int l16 = lane >> 2;                        // row within 16
    const int csA = (lane & 3) ^ ((lane >> 3) & 3);   // inverse-swizzled src chunk

    // stage K-step kc into dbuf: Ah + Al + B = 3 gload_lds per wave
    auto stageT = [&](int dbuf, int kc) {
        const int r0 = wave * 16;                     // wave-uniform row base
        const size_t ga = (size_t)(m0 + r0 + l16) * 1024 + kc * 32 + csA * 8;
        GLOAD16(Ahp + ga, &AhS[dbuf][r0 * 32]);
        GLOAD16(Alp + ga, &AlS[dbuf][r0 * 32]);
        const size_t gb = ((size_t)(n16base + wave) * 32 + kc) * 512 + lane * 8;
        GLOAD16(Bf + gb, &BS[dbuf][wave * 512]);
    };

    floatx4 acc[4][2];
    const floatx4 zz = {0.f, 0.f, 0.f, 0.f};
    #pragma unroll
    for (int i = 0; i < 4; ++i)
        #pragma unroll
        for (int j = 0; j < 2; ++j) acc[i][j] = zz;

    // prologue
    stageT(0, 0);
    asm volatile("s_waitcnt vmcnt(0)" ::: "memory");
    __builtin_amdgcn_s_barrier();
    asm volatile("" ::: "memory");

    int cur = 0;
    for (int T = 0; T < 32; ++T) {
        const int nxt = cur ^ 1;
        if (T < 31) {
            stageT(nxt, T + 1);                              // +3 in flight
            asm volatile("s_waitcnt vmcnt(3)" ::: "memory"); // T's batch landed
        } else {
            asm volatile("s_waitcnt vmcnt(0)" ::: "memory");
        }
        __builtin_amdgcn_s_barrier();                        // buf[cur] visible
        asm volatile("" ::: "memory");
        bf16x8 ah[4], al[4], bb[2];
        #pragma unroll
        for (int mi = 0; mi < 4; ++mi) {
            const int rr2 = wm + mi * 16 + m16;
            const int ch = q ^ ((m16 >> 1) & 3);             // swizzled chunk
            ah[mi] = *(const bf16x8*)&AhS[cur][rr2 * 32 + ch * 8];
            al[mi] = *(const bf16x8*)&AlS[cur][rr2 * 32 + ch * 8];
        }
        #pragma unroll
        for (int j = 0; j < 2; ++j)
            bb[j] = *(const bf16x8*)&BS[cur][((wn >> 4) + j) * 512 + lane * 8];
        __builtin_amdgcn_s_setprio(1);
        #pragma unroll
        for (int mi = 0; mi < 4; ++mi)
            #pragma unroll
            for (int j = 0; j < 2; ++j) {
                acc[mi][j] = __builtin_amdgcn_mfma_f32_16x16x32_bf16(ah[mi], bb[j], acc[mi][j], 0, 0, 0);
                acc[mi][j] = __builtin_amdgcn_mfma_f32_16x16x32_bf16(al[mi], bb[j], acc[mi][j], 0, 0, 0);
            }
        __builtin_amdgcn_s_setprio(0);
        asm volatile("" ::: "memory");
        __builtin_amdgcn_s_barrier();                        // reads done before
        asm volatile("" ::: "memory");                       // next overwrite
        cur = nxt;
    }

    #pragma unroll
    for (int i = 0; i < 4; ++i) {
        const int row_b = m0 + wm + i * 16 + q * 4;
        #pragma unroll
        for (int j = 0; j < 2; ++j) {
            const int col = n0 + wn + j * 16 + m16;
            #pragma unroll
            for (int rr = 0; rr < 4; ++rr) {
                const int row = row_b + rr;
                const float v = acc[i][j][rr];
                if (n0 < 2048) {
                    const int b = row >> 11, l = row & 2047;
                    XSP[((size_t)b * 2051 + l + 3) * 2048 + col] = f2bf(v);
                } else {
                    RES[(size_t)row * 2048 + (col - 2048)] = v;
                }
            }
        }
    }
}

// ---------------------------------------------------------------------------
// Conv as MFMA GEMM — r7's verified best (79.5 µs): 8-wave kc-half pipelined
// schedule + 8x8 XCD L2-locality tile map. (r8's 256x128 at 1 block/CU
// regressed to 94.9 — 2 waves/SIMD can't hide latency; reverted.)
// ---------------------------------------------------------------------------
__global__ __launch_bounds__(512, 4) void conv2(
    const ushort_t* __restrict__ Xh, const ushort_t* __restrict__ Bf,
    const float* __restrict__ bias, uint_t* __restrict__ Upk)
{
    __shared__ __align__(16) ushort_t Asw[2][2][128 * 32];   // 32 KiB
    __shared__ __align__(16) ushort_t Bsw[2][2][8 * 512];    // 32 KiB
    const int t = threadIdx.x;
    const int lin = blockIdx.x, xcd = lin & 7, s = lin >> 3;   // s in [0,64)
    const int by  = (xcd >> 1) * 8 + (s & 7);    // r6-verified L2 tile map
    const int bxp = (xcd & 1) * 8 + (s >> 3);
    const int m0 = by * 128, n0 = bxp * 128;
    const int g1024 = (n0 >= 1024) ? 1024 : 0;
    const int lane = t & 63, wave = t >> 6;          // wave 0..7
    const int wm = (wave >> 2) * 64, wn = (wave & 3) * 32;
    const int m16 = lane & 15, q = lane >> 4;
    const int n16base = n0 >> 4;
    const int Xrow0 = (m0 >> 11) * 2051 + (m0 & 2047);   // b*2051 + l-base
    // staging lane geometry for A: 1KB issue = 16 rows x 4 chunks(16B)
    const int l16 = lane >> 2;                        // row within 16
    const int csA = (lane & 3) ^ ((lane >> 3) & 3);   // inverse-swizzled src chunk

    // stage kc-half kcL of tile Tn into dbuf: 1 A-issue + 1 B-issue per wave
    auto stageT = [&](int dbuf, int kcL, int Tn) {
        const int wtap = Tn >> 4;                     // conv tap, const per tile
        const int i0 = ((Tn << 6) & 1023) + kcL * 32; // k-col within tap group
        const int kc = Tn * 2 + kcL;
        {
            const int r0 = wave * 16;                 // wave-uniform row base
            const size_t gidx = (size_t)(Xrow0 + r0 + l16 + wtap) * 2048
                              + g1024 + i0 + csA * 8;
            GLOAD16(Xh + gidx, &Asw[dbuf][kcL][r0 * 32]);
        }
        {
            const size_t gidx = ((size_t)(n16base + wave) * 128 + kc) * 512 + lane * 8;
            GLOAD16(Bf + gidx, &Bsw[dbuf][kcL][wave * 512]);
        }
    };

    floatx4 acc[4][2];
    const floatx4 zz = {0.f, 0.f, 0.f, 0.f};
    #pragma unroll
    for (int i = 0; i < 4; ++i)
        #pragma unroll
        for (int j = 0; j < 2; ++j) acc[i][j] = zz;

    bf16x8 a0[4], b0[2], a1[4], b1[2];

    auto readA = [&](int dbuf, int kcL, bf16x8 (&ah)[4]) {
        #pragma unroll
        for (int mi = 0; mi < 4; ++mi) {
            const int rr2 = wm + mi * 16 + m16;
            const int ch = q ^ ((m16 >> 1) & 3);      // swizzled chunk
            ah[mi] = *(const bf16x8*)&Asw[dbuf][kcL][rr2 * 32 + ch * 8];
        }
    };
    auto readB = [&](int dbuf, int kcL, bf16x8 (&bb)[2]) {
        #pragma unroll
        for (int j = 0; j < 2; ++j)
            bb[j] = *(const bf16x8*)&Bsw[dbuf][kcL][((wn >> 4) + j) * 512 + lane * 8];
    };
    auto mfma8 = [&](bf16x8 (&ah)[4], bf16x8 (&bb)[2]) {
        __builtin_amdgcn_s_setprio(1);
        #pragma unroll
        for (int mi = 0; mi < 4; ++mi)
            #pragma unroll
            for (int j = 0; j < 2; ++j)
                acc[mi][j] = __builtin_amdgcn_mfma_f32_16x16x32_bf16(ah[mi], bb[j], acc[mi][j], 0, 0, 0);
        __builtin_amdgcn_s_setprio(0);
    };

    // prologue: stage tile 0 (both halves), wait kc0, preload regs
    stageT(0, 0, 0);
    stageT(0, 1, 0);
    asm volatile("s_waitcnt vmcnt(2)" ::: "memory");
    __builtin_amdgcn_s_barrier();
    asm volatile("" ::: "memory");
    readA(0, 0, a0); readB(0, 0, b0);

    int cur = 0;
    for (int T = 0; T < 64; ++T) {
        const int nxt = cur ^ 1;
        if (T < 63) {
            stageT(nxt, 0, T + 1);                       // +2 (T+1,kc0)
            asm volatile("s_waitcnt vmcnt(2)" ::: "memory");   // (T,kc1) landed
        } else {
            asm volatile("s_waitcnt vmcnt(0)" ::: "memory");
        }
        __builtin_amdgcn_s_barrier();                    // (T,kc1) visible
        asm volatile("" ::: "memory");
        readA(cur, 1, a1); readB(cur, 1, b1);            // fly under next MFMA
        mfma8(a0, b0);                                   // consume (T,kc0)
        if (T < 63) stageT(nxt, 1, T + 1);               // +2 (T+1,kc1)
        mfma8(a1, b1);                                   // consume (T,kc1)
        asm volatile("" ::: "memory");
        if (T < 63) {
            asm volatile("s_waitcnt vmcnt(2)" ::: "memory");   // (T+1,kc0) landed
            __builtin_amdgcn_s_barrier();                // visible; all reads of
            asm volatile("" ::: "memory");               // buf[cur] consumed above
            readA(nxt, 0, a0); readB(nxt, 0, b0);        // fly under next iter
        }
        cur = nxt;
    }

    #pragma unroll
    for (int i = 0; i < 4; ++i) {
        const int row_b = m0 + wm + i * 16 + q * 4;
        #pragma unroll
        for (int j = 0; j < 2; ++j) {
            const int col = n0 + wn + j * 16 + m16;
            const float bz = bias[col];
            #pragma unroll
            for (int rr = 0; rr < 4; ++rr) {
                const int row = row_b + rr;
                const float v = silu_f(acc[i][j][rr] + bz);
                Upk[(size_t)row * 2048 + col] = packhl(v);
            }
        }
    }
}

// Sum the 4 split-K partials of dbc.
__global__ __launch_bounds__(256) void dbc_reduce(
    const float* __restrict__ DBCP, float* __restrict__ DBC)
{
    const int i = blockIdx.x * 256 + threadIdx.x;   // < 393216
    DBC[i] = (DBCP[i] + DBCP[393216 + i]) + (DBCP[786432 + i] + DBCP[1179648 + i]);
}

// ---------------------------------------------------------------------------
// delta[p,d] = clip(softplus(dbc[p,0:64] @ W_dt[:,d] + b_dt[d]), 1e-3, 1e-1)
// ---------------------------------------------------------------------------
__global__ __launch_bounds__(256) void delta_kernel(
    const float* __restrict__ DBC, const float* __restrict__ W_dt,
    const float* __restrict__ b_dt, float* __restrict__ DELTA)
{
    const int n  = blockIdx.x * 256 + threadIdx.x;
    const int p0 = blockIdx.y * 16;
    const int t  = threadIdx.x;
    __shared__ float dt_s[16][64];
    #pragma unroll
    for (int j = 0; j < 4; ++j) {
        const int lin = j * 256 + t;
        const int r = lin >> 6, k = lin & 63;
        dt_s[r][k] = DBC[(size_t)(p0 + r) * 96 + k];
    }
    __syncthreads();
    float acc[16];
    const float bz = b_dt[n];
    #pragma unroll
    for (int r = 0; r < 16; ++r) acc[r] = bz;
    for (int k = 0; k < 64; ++k) {
        const float wv = W_dt[(size_t)k * 2048 + n];
        #pragma unroll
        for (int r = 0; r < 16; ++r) acc[r] += dt_s[r][k] * wv;
    }
    #pragma unroll
    for (int r = 0; r < 16; ++r) {
        float a = acc[r];
        float sp = (a > 20.f) ? a : log1pf(expf(a));
        sp = fminf(fmaxf(sp, 0.001f), 0.1f);
        DELTA[(size_t)(p0 + r) * 2048 + n] = sp;
    }
}

// ---------------------------------------------------------------------------
// Chunked scan (64 chunks of 32). HEND/HINIT [c][b][d][16n]; SD[c][b][d].
// ---------------------------------------------------------------------------
__global__ __launch_bounds__(256) void scan_p1(
    const float* __restrict__ DELTA, const uint_t* __restrict__ Upk,
    const float* __restrict__ DBC, const float* __restrict__ A_log,
    float* __restrict__ HEND, float* __restrict__ SD)
{
    const int t = threadIdx.x;
    const int d = blockIdx.x * 256 + t;
    const int c = blockIdx.y;
    const int b = blockIdx.z;
    const int p0 = b * 2048 + c * 32;
    __shared__ float Bs[32][16];
    for (int lin = t; lin < 512; lin += 256) {
        const int s = lin >> 4, n = lin & 15;
        Bs[s][n] = DBC[(size_t)(p0 + s) * 96 + 64 + n];
    }
    __syncthreads();
    float Af[16];
    *(float4*)&Af[0]  = *(const float4*)&A_log[(size_t)d * 16 + 0];
    *(float4*)&Af[4]  = *(const float4*)&A_log[(size_t)d * 16 + 4];
    *(float4*)&Af[8]  = *(const float4*)&A_log[(size_t)d * 16 + 8];
    *(float4*)&Af[12] = *(const float4*)&A_log[(size_t)d * 16 + 12];
    #pragma unroll
    for (int n = 0; n < 16; ++n) Af[n] = -__expf(Af[n]);

    float h[16] = {};
    float sd = 0.f;
    for (int s = 0; s < 32; ++s) {
        const size_t ix = (size_t)(p0 + s) * 2048 + d;
        const float dv = DELTA[ix];
        const float uv = unpack_sum(Upk[ix]);
        const float du = dv * uv;
        sd += dv;
        #pragma unroll
        for (int n = 0; n < 16; ++n)
            h[n] = __expf(dv * Af[n]) * h[n] + du * Bs[s][n];
    }
    const size_t hb = (((size_t)c * 2 + b) * 2048 + d) * 16;
    *(float4*)&HEND[hb + 0]  = *(float4*)&h[0];
    *(float4*)&HEND[hb + 4]  = *(float4*)&h[4];
    *(float4*)&HEND[hb + 8]  = *(float4*)&h[8];
    *(float4*)&HEND[hb + 12] = *(float4*)&h[12];
    SD[((size_t)c * 2 + b) * 2048 + d] = sd;
}

__global__ __launch_bounds__(256) void scan_p2(
    const float* __restrict__ HEND, const float* __restrict__ SD,
    const float* __restrict__ A_log, float* __restrict__ HINIT)
{
    const int g = blockIdx.x * 256 + threadIdx.x;   // < 65536
    const int n = g & 15, d = (g >> 4) & 2047, b = (g >> 15) & 1;
    const float Af = -__expf(A_log[(size_t)d * 16 + n]);
    float h = 0.f;
    #pragma unroll 8
    for (int c = 0; c < 64; ++c) {
        const size_t cb = (size_t)c * 2 + b;
        const size_t idx = (cb * 2048 + d) * 16 + n;
        HINIT[idx] = h;
        h = __expf(Af * SD[cb * 2048 + d]) * h + HEND[idx];
    }
}

// Pass 3: re-scan from h_init, y, gate; emit G packed hi|lo.
__global__ __launch_bounds__(256) void scan_p3(
    const float* __restrict__ DELTA, const uint_t* __restrict__ Upk,
    const float* __restrict__ DBC, const float* __restrict__ RES,
    const float* __restrict__ A_log, const float* __restrict__ Dp,
    const float* __restrict__ HINIT, uint_t* __restrict__ Gpk)
{
    const int t = threadIdx.x;
    const int d = blockIdx.x * 256 + t;
    const int c = blockIdx.y;
    const int b = blockIdx.z;
    const int p0 = b * 2048 + c * 32;
    __shared__ float Bs[32][16];
    __shared__ float Cs[32][16];
    for (int lin = t; lin < 512; lin += 256) {
        const int s = lin >> 4, n = lin & 15;
        Bs[s][n] = DBC[(size_t)(p0 + s) * 96 + 64 + n];
        Cs[s][n] = DBC[(size_t)(p0 + s) * 96 + 80 + n];
    }
    __syncthreads();
    float Af[16];
    *(float4*)&Af[0]  = *(const float4*)&A_log[(size_t)d * 16 + 0];
    *(float4*)&Af[4]  = *(const float4*)&A_log[(size_t)d * 16 + 4];
    *(float4*)&Af[8]  = *(const float4*)&A_log[(size_t)d * 16 + 8];
    *(float4*)&Af[12] = *(const float4*)&A_log[(size_t)d * 16 + 12];
    #pragma unroll
    for (int n = 0; n < 16; ++n) Af[n] = -__expf(Af[n]);

    const size_t hb = (((size_t)c * 2 + b) * 2048 + d) * 16;
    float h[16];
    *(float4*)&h[0]  = *(const float4*)&HINIT[hb + 0];
    *(float4*)&h[4]  = *(const float4*)&HINIT[hb + 4];
    *(float4*)&h[8]  = *(const float4*)&HINIT[hb + 8];
    *(float4*)&h[12] = *(const float4*)&HINIT[hb + 12];
    const float Dd = Dp[d];

    for (int s = 0; s < 32; ++s) {
        const int p = p0 + s;
        const size_t ix = (size_t)p * 2048 + d;
        const float dv = DELTA[ix];
        const float uv = unpack_sum(Upk[ix]);
        const float du = dv * uv;
        float y = 0.f;
        #pragma unroll
        for (int n = 0; n < 16; ++n) {
            h[n] = __expf(dv * Af[n]) * h[n] + du * Bs[s][n];
            y += h[n] * Cs[s][n];
        }
        const float resv = RES[ix];
        const float gv = (y + uv * Dd) * silu_f(resv);
        Gpk[ix] = packhl(gv);
    }
}

// ---------------------------------------------------------------------------
extern "C" void kernel_launch(void* const* d_in, const int* in_sizes, int n_in,
                              void* d_out, int out_size, void* d_ws, size_t ws_size,
                              hipStream_t stream) {
    const float* x      = (const float*)d_in[0];
    const float* W_in   = (const float*)d_in[1];
    const float* conv_k = (const float*)d_in[2];
    const float* conv_b = (const float*)d_in[3];
    const float* W_x    = (const float*)d_in[4];
    const float* W_dt   = (const float*)d_in[5];
    const float* b_dt   = (const float*)d_in[6];
    const float* A_log  = (const float*)d_in[7];
    const float* Dv     = (const float*)d_in[8];
    const float* W_out  = (const float*)d_in[9];
    float* out = (float*)d_out;

    char* base = (char*)d_ws;
    float*    RES      = (float*)(base);                  // 33,554,432
    uint_t*   Upk      = (uint_t*)(base + 33554432);      // 33,554,432
    float*    DELTA    = (float*)(base + 67108864);       // 33,554,432
    ushort_t* XSP_h    = (ushort_t*)(base + 100663296);   // 16,801,792 (2 x 2051 x 2048)
    float*    HEND     = (float*)(base + 100663296);      // alias over XSP (dead after conv2)
    ushort_t* xh       = (ushort_t*)(base + 117465088);   //  8,388,608 (x hi plane)
    ushort_t* xl       = (ushort_t*)(base + 125853696);   //  8,388,608 (x lo plane)
    ushort_t* convkF   = (ushort_t*)(base + 134242304);   // 16,777,216
    uint_t*   Gpk      = (uint_t*)(base + 117465088);     // alias over xh+xl+convkF (dead)
    ushort_t* WinF     = (ushort_t*)(base + 151019520);   //  8,388,608
    ushort_t* WoutF    = (ushort_t*)(base + 159408128);   //  4,194,304
    ushort_t* WxF      = (ushort_t*)(base + 163602432);   //    524,288
    float*    DBCP     = (float*)(base + 164126720);      //  6,291,456
    float*    DBC      = (float*)(base + 170418176);      //  1,572,864
    float*    SD       = (float*)(base + 171991040);      //  1,048,576
    float*    HINIT    = (float*)(base + 173039616);      // 16,777,216

    // 0) all prep in one launch (x -> xh/xl split planes)
    prep_all<<<19504, 256, 0, stream>>>(x, W_in, conv_k, W_out, W_x,
                                        xh, xl, WinF, convkF, WoutF, WxF, XSP_h);
    // 1) xz: xs -> XSP bf16 hi (+pad), res -> RES fp32 (pipelined gload_lds)
    gemm0p<<<1024, 512, 0, stream>>>(xh, xl, WinF, RES, XSP_h);
    // 2) u = silu(conv + b) -> Upk (r7 schedule + XCD L2 tile map)
    conv2<<<512, 512, 0, stream>>>(XSP_h, convkF, conv_b, Upk);
    // 3) dbc = U @ W_x, split-K x4 + reduce
    gemm2<2><<<dim3(4, 32), 256, 0, stream>>>(Upk, WxF, 2048, DBCP, nullptr);
    dbc_reduce<<<1536, 256, 0, stream>>>(DBCP, DBC);
    // 4) delta
    delta_kernel<<<dim3(8, 256), 256, 0, stream>>>(DBC, W_dt, b_dt, DELTA);
    // 5) chunked scan
    scan_p1<<<dim3(8, 64, 2), 256, 0, stream>>>(DELTA, Upk, DBC, A_log, HEND, SD);
    scan_p2<<<256, 256, 0, stream>>>(HEND, SD, A_log, HINIT);
    scan_p3<<<dim3(8, 64, 2), 256, 0, stream>>>(DELTA, Upk, DBC, RES, A_log, Dv,
                                                HINIT, Gpk);
    // 6) out = G @ W_out
    gemm2<1><<<256, 256, 0, stream>>>(Gpk, WoutF, 2048, out, nullptr);
}

// Round 10
// 453.892 us; speedup vs baseline: 1.0607x; 1.0438x over previous
//
#include <hip/hip_runtime.h>
#include <math.h>

// B=2, L=2048, D_MODEL=1024, D_INNER=2048, D_STATE=16, DT_RANK=64, D_CONV=4
// P = B*L = 4096

typedef unsigned short ushort_t;
typedef unsigned int uint_t;
typedef __bf16 bf16x8 __attribute__((ext_vector_type(8)));
typedef float floatx4 __attribute__((ext_vector_type(4)));

#define LDS_STRIDE 40   // 32 + 8 pad shorts

#define GLOAD16(gp, lp) \
    __builtin_amdgcn_global_load_lds((const __attribute__((address_space(1))) void*)(gp), \
                                     (__attribute__((address_space(3))) void*)(lp), 16, 0, 0)

__device__ __forceinline__ float silu_f(float x) { return x / (1.0f + __expf(-x)); }

__device__ __forceinline__ unsigned short f2bf(float f) {
    unsigned u = __float_as_uint(f);
    unsigned r = u + 0x7fffu + ((u >> 16) & 1u);   // RNE (finite values only)
    return (unsigned short)(r >> 16);
}
__device__ __forceinline__ float bf2f(unsigned short h) {
    return __uint_as_float(((unsigned)h) << 16);
}
__device__ __forceinline__ uint_t packhl(float v) {
    const unsigned short h = f2bf(v);
    const unsigned short l = f2bf(v - bf2f(h));
    return (uint_t)h | ((uint_t)l << 16);
}
__device__ __forceinline__ float unpack_sum(uint_t pk) {
    return __uint_as_float(pk << 16) + __uint_as_float(pk & 0xffff0000u);
}
__device__ __forceinline__ void unpack8(uint4 w0, uint4 w1, uint4& H, uint4& L) {
    H.x = (w0.x & 0xffffu) | (w0.y << 16);  L.x = (w0.x >> 16) | (w0.y & 0xffff0000u);
    H.y = (w0.z & 0xffffu) | (w0.w << 16);  L.y = (w0.z >> 16) | (w0.w & 0xffff0000u);
    H.z = (w1.x & 0xffffu) | (w1.y << 16);  L.z = (w1.x >> 16) | (w1.y & 0xffff0000u);
    H.w = (w1.z & 0xffffu) | (w1.w << 16);  L.w = (w1.z >> 16) | (w1.w & 0xffff0000u);
}
// MFMA B-fragment-ordered address for B^T matrix [N][K]:
// lane (m16 + 16*q) of tile (n16, kc) holds B^T[n16*16+m16][kc*32+q*8 .. +8]
__device__ __forceinline__ size_t faddr(int n, int k, int KC) {
    return ((size_t)((n >> 4) * KC + (k >> 5)) * 64 + (n & 15) + (((k >> 3) & 3) << 4)) * 8
           + (k & 7);
}

// ---------------------------------------------------------------------------
// Mega prep kernel (block-range switch). All B-operands written in
// MFMA-fragment order (bf16 hi only). x split into xh/xl bf16 planes.
// ---------------------------------------------------------------------------
__global__ __launch_bounds__(256) void prep_all(
    const float* __restrict__ x, const float* __restrict__ W_in,
    const float* __restrict__ conv_k, const float* __restrict__ W_out,
    const float* __restrict__ W_x,
    ushort_t* __restrict__ xh, ushort_t* __restrict__ xl,
    ushort_t* __restrict__ WinF, ushort_t* __restrict__ convkF,
    ushort_t* __restrict__ WoutF, ushort_t* __restrict__ WxF,
    ushort_t* __restrict__ XSP_h)
{
    __shared__ float ts[32][33];
    const int bid = blockIdx.x;
    const int t = threadIdx.x;
    if (bid < 4096) {
        const size_t i4 = ((size_t)bid * 256 + t) * 4;
        float4 v = *(const float4*)&x[i4];
        ushort4 h, l;
        h.x = f2bf(v.x); l.x = f2bf(v.x - bf2f(h.x));
        h.y = f2bf(v.y); l.y = f2bf(v.y - bf2f(h.y));
        h.z = f2bf(v.z); l.z = f2bf(v.z - bf2f(h.z));
        h.w = f2bf(v.w); l.w = f2bf(v.w - bf2f(h.w));
        *(ushort4*)&xh[i4] = h;
        *(ushort4*)&xl[i4] = l;
        return;
    }
    if (bid >= 18432 && bid < 19456) {
        const int idx = (bid - 18432) * 256 + t;
        const int r = idx >> 11, k = idx & 2047;
        float v = (r < 96) ? W_x[(size_t)k * 96 + r] : 0.f;
        WxF[faddr(r, k, 64)] = f2bf(v);
        return;
    }
    if (bid >= 19456) {
        const int idx = (bid - 19456) * 256 + t;   // < 12288
        const int b = idx / 6144, rem = idx % 6144;
        const int lp = rem >> 11, c = rem & 2047;
        XSP_h[((size_t)b * 2051 + lp) * 2048 + c] = 0;
        return;
    }
    // transpose + fragment-order cases (dst is B^T [N=C][K=R])
    const float* src; int R, C, KC; ushort_t* dst; int bx, by;
    if (bid < 8192)       { src = W_in;   R = 1024; C = 4096; KC = 32;  dst = WinF;
                            int l = bid - 4096;  bx = l & 127; by = l >> 7; }
    else if (bid < 16384) { src = conv_k; R = 4096; C = 2048; KC = 128; dst = convkF;
                            int l = bid - 8192;  bx = l & 63;  by = l >> 6; }
    else                  { src = W_out;  R = 2048; C = 1024; KC = 64;  dst = WoutF;
                            int l = bid - 16384; bx = l & 31;  by = l >> 5; }
    const int tx = t & 31, ty = t >> 5;
    const int r0 = by * 32, c0 = bx * 32;
    #pragma unroll
    for (int j = 0; j < 4; ++j)
        ts[ty + j * 8][tx] = src[(size_t)(r0 + ty + j * 8) * C + c0 + tx];
    __syncthreads();
    #pragma unroll
    for (int j = 0; j < 4; ++j) {
        const int n = c0 + ty + j * 8, k = r0 + tx;
        dst[faddr(n, k, KC)] = f2bf(ts[tx][ty + j * 8]);
    }
}

// ---------------------------------------------------------------------------
// 2-term split-bf16 MFMA GEMM, packed A, fragment-ordered direct-global B.
// Only MODE 2 (dbc split-K) is used now.
// ---------------------------------------------------------------------------
template<int MODE>
__global__ __launch_bounds__(256) void gemm2(
    const uint_t* __restrict__ Apk, const ushort_t* __restrict__ Bf, int Kfull,
    float* __restrict__ Cf, ushort_t* __restrict__ Oh)
{
    __shared__ __align__(16) ushort_t As_h[128 * LDS_STRIDE];
    __shared__ __align__(16) ushort_t As_l[128 * LDS_STRIDE];
    const int t = threadIdx.x;
    int bx, by;
    if (MODE == 2) { bx = blockIdx.x; by = blockIdx.y; }
    else {
        const int lin = blockIdx.x, xcd = lin & 7, s = lin >> 3;
        bx = s >> 2;
        by = xcd * 4 + (s & 3);
    }
    const int m0 = by * 128;
    const int n0 = (MODE == 2) ? 0 : bx * 128;
    const int kbeg = (MODE == 2) ? bx * 512 : 0;
    const int kend = (MODE == 2) ? kbeg + 512 : Kfull;
    const int KC = Kfull >> 5;
    const int lane = t & 63, wave = t >> 6;
    const int wm = (wave >> 1) * 64, wn = (wave & 1) * 64;
    const int m16 = lane & 15, q = lane >> 4;
    const int n16b = (n0 + wn) >> 4;
    const int r_0 = t >> 2, cc_0 = (t & 3) * 8;
    const int r_1 = (t + 256) >> 2, cc_1 = ((t + 256) & 3) * 8;

    uint4 a00 = *(const uint4*)&Apk[(size_t)(m0 + r_0) * Kfull + kbeg + cc_0];
    uint4 a01 = *(const uint4*)&Apk[(size_t)(m0 + r_0) * Kfull + kbeg + cc_0 + 4];
    uint4 a10 = *(const uint4*)&Apk[(size_t)(m0 + r_1) * Kfull + kbeg + cc_1];
    uint4 a11 = *(const uint4*)&Apk[(size_t)(m0 + r_1) * Kfull + kbeg + cc_1 + 4];
    bf16x8 bc[4];
    {
        const int kc = kbeg >> 5;
        #pragma unroll
        for (int j = 0; j < 4; ++j)
            bc[j] = *(const bf16x8*)&Bf[(((size_t)(n16b + j) * KC + kc) * 64 + lane) * 8];
    }

    floatx4 acc[4][4];
    const floatx4 zz = {0.f, 0.f, 0.f, 0.f};
    #pragma unroll
    for (int i = 0; i < 4; ++i)
        #pragma unroll
        for (int j = 0; j < 4; ++j) acc[i][j] = zz;

    for (int k0 = kbeg; k0 < kend; k0 += 32) {
        uint4 H, L;
        unpack8(a00, a01, H, L);
        *(uint4*)&As_h[r_0 * LDS_STRIDE + cc_0] = H;
        *(uint4*)&As_l[r_0 * LDS_STRIDE + cc_0] = L;
        unpack8(a10, a11, H, L);
        *(uint4*)&As_h[r_1 * LDS_STRIDE + cc_1] = H;
        *(uint4*)&As_l[r_1 * LDS_STRIDE + cc_1] = L;
        __syncthreads();
        bf16x8 bn[4];
        if (k0 + 32 < kend) {
            const int kn = k0 + 32, kc = kn >> 5;
            a00 = *(const uint4*)&Apk[(size_t)(m0 + r_0) * Kfull + kn + cc_0];
            a01 = *(const uint4*)&Apk[(size_t)(m0 + r_0) * Kfull + kn + cc_0 + 4];
            a10 = *(const uint4*)&Apk[(size_t)(m0 + r_1) * Kfull + kn + cc_1];
            a11 = *(const uint4*)&Apk[(size_t)(m0 + r_1) * Kfull + kn + cc_1 + 4];
            #pragma unroll
            for (int j = 0; j < 4; ++j)
                bn[j] = *(const bf16x8*)&Bf[(((size_t)(n16b + j) * KC + kc) * 64 + lane) * 8];
        }
        bf16x8 ah[4], al[4];
        #pragma unroll
        for (int i = 0; i < 4; ++i) {
            const int off = (wm + i * 16 + m16) * LDS_STRIDE + q * 8;
            ah[i] = *(const bf16x8*)&As_h[off];
            al[i] = *(const bf16x8*)&As_l[off];
        }
        #pragma unroll
        for (int i = 0; i < 4; ++i)
            #pragma unroll
            for (int j = 0; j < 4; ++j) {
                acc[i][j] = __builtin_amdgcn_mfma_f32_16x16x32_bf16(ah[i], bc[j], acc[i][j], 0, 0, 0);
                acc[i][j] = __builtin_amdgcn_mfma_f32_16x16x32_bf16(al[i], bc[j], acc[i][j], 0, 0, 0);
            }
        #pragma unroll
        for (int j = 0; j < 4; ++j) bc[j] = bn[j];
        __syncthreads();
    }

    float* Cp = (MODE == 2) ? (Cf + (size_t)bx * 393216) : Cf;
    #pragma unroll
    for (int i = 0; i < 4; ++i) {
        const int row_b = m0 + wm + i * 16 + q * 4;
        #pragma unroll
        for (int j = 0; j < 4; ++j) {
            const int col = n0 + wn + j * 16 + m16;
            #pragma unroll
            for (int rr = 0; rr < 4; ++rr) {
                const int row = row_b + rr;
                const float v = acc[i][j][rr];
                if (MODE == 1) {
                    Cp[(size_t)row * 1024 + col] = v;
                } else {
                    if (col < 96) Cp[(size_t)row * 96 + col] = v;
                }
            }
        }
    }
}

// ---------------------------------------------------------------------------
// gemm0p: xz GEMM, pipelined gload_lds structure. Wave grid switched to
// 4M x 2N (wave tile 32x64): A is DUAL-plane (hi+lo) so tall-N waves cut
// per-wave ds_reads 10 -> 8 (2Ah+2Al+4B) => LDS floor ~65 -> ~55 µs.
// ---------------------------------------------------------------------------
__global__ __launch_bounds__(512, 4) void gemm0p(
    const ushort_t* __restrict__ Ahp, const ushort_t* __restrict__ Alp,
    const ushort_t* __restrict__ Bf,
    float* __restrict__ RES, ushort_t* __restrict__ XSP)
{
    __shared__ __align__(16) ushort_t AhS[2][128 * 32];   // 16 KiB
    __shared__ __align__(16) ushort_t AlS[2][128 * 32];   // 16 KiB
    __shared__ __align__(16) ushort_t BS[2][8 * 512];     // 16 KiB
    const int t = threadIdx.x;
    const int lin = blockIdx.x, xcd = lin & 7, s = lin >> 3;   // s in [0,128)
    const int by = (xcd >> 1) * 8 + (s & 7);     // [0,32)
    const int bx = (xcd & 1) * 16 + (s >> 3);    // [0,32)
    const int m0 = by * 128, n0 = bx * 128;
    const int lane = t & 63, wave = t >> 6;          // wave 0..7
    const int wm = (wave & 3) * 32, wn = (wave >> 2) * 64;   // 4M x 2N
    const int m16 = lane & 15, q = lane >> 4;
    const int n16base = n0 >> 4;
    const int l16 = lane >> 2;                        // row within 16
    const int csA = (lane & 3) ^ ((lane >> 3) & 3);   // inverse-swizzled src chunk

    // stage K-step kc into dbuf: Ah + Al + B = 3 gload_lds per wave
    auto stageT = [&](int dbuf, int kc) {
        const int r0 = wave * 16;                     // wave-uniform row base
        const size_t ga = (size_t)(m0 + r0 + l16) * 1024 + kc * 32 + csA * 8;
        GLOAD16(Ahp + ga, &AhS[dbuf][r0 * 32]);
        GLOAD16(Alp + ga, &AlS[dbuf][r0 * 32]);
        const size_t gb = ((size_t)(n16base + wave) * 32 + kc) * 512 + lane * 8;
        GLOAD16(Bf + gb, &BS[dbuf][wave * 512]);
    };

    floatx4 acc[2][4];
    const floatx4 zz = {0.f, 0.f, 0.f, 0.f};
    #pragma unroll
    for (int i = 0; i < 2; ++i)
        #pragma unroll
        for (int j = 0; j < 4; ++j) acc[i][j] = zz;

    // prologue
    stageT(0, 0);
    asm volatile("s_waitcnt vmcnt(0)" ::: "memory");
    __builtin_amdgcn_s_barrier();
    asm volatile("" ::: "memory");

    int cur = 0;
    for (int T = 0; T < 32; ++T) {
        const int nxt = cur ^ 1;
        if (T < 31) {
            stageT(nxt, T + 1);                              // +3 in flight
            asm volatile("s_waitcnt vmcnt(3)" ::: "memory"); // T's batch landed
        } else {
            asm volatile("s_waitcnt vmcnt(0)" ::: "memory");
        }
        __builtin_amdgcn_s_barrier();                        // buf[cur] visible
        asm volatile("" ::: "memory");
        bf16x8 ah[2], al[2], bb[4];
        #pragma unroll
        for (int mi = 0; mi < 2; ++mi) {
            const int rr2 = wm + mi * 16 + m16;
            const int ch = q ^ ((m16 >> 1) & 3);             // swizzled chunk
            ah[mi] = *(const bf16x8*)&AhS[cur][rr2 * 32 + ch * 8];
            al[mi] = *(const bf16x8*)&AlS[cur][rr2 * 32 + ch * 8];
        }
        #pragma unroll
        for (int j = 0; j < 4; ++j)
            bb[j] = *(const bf16x8*)&BS[cur][((wn >> 4) + j) * 512 + lane * 8];
        __builtin_amdgcn_s_setprio(1);
        #pragma unroll
        for (int mi = 0; mi < 2; ++mi)
            #pragma unroll
            for (int j = 0; j < 4; ++j) {
                acc[mi][j] = __builtin_amdgcn_mfma_f32_16x16x32_bf16(ah[mi], bb[j], acc[mi][j], 0, 0, 0);
                acc[mi][j] = __builtin_amdgcn_mfma_f32_16x16x32_bf16(al[mi], bb[j], acc[mi][j], 0, 0, 0);
            }
        __builtin_amdgcn_s_setprio(0);
        asm volatile("" ::: "memory");
        __builtin_amdgcn_s_barrier();                        // reads done before
        asm volatile("" ::: "memory");                       // next overwrite
        cur = nxt;
    }

    #pragma unroll
    for (int i = 0; i < 2; ++i) {
        const int row_b = m0 + wm + i * 16 + q * 4;
        #pragma unroll
        for (int j = 0; j < 4; ++j) {
            const int col = n0 + wn + j * 16 + m16;
            #pragma unroll
            for (int rr = 0; rr < 4; ++rr) {
                const int row = row_b + rr;
                const float v = acc[i][j][rr];
                if (n0 < 2048) {
                    const int b = row >> 11, l = row & 2047;
                    XSP[((size_t)b * 2051 + l + 3) * 2048 + col] = f2bf(v);
                } else {
                    RES[(size_t)row * 2048 + (col - 2048)] = v;
                }
            }
        }
    }
}

// ---------------------------------------------------------------------------
// gemm1p: out GEMM (4096x1024, K=2048, 2-term) — pipelined plane structure
// with split-K x2 for occupancy. Old gemm2<1> ran 256 blocks x 4 waves =
// 1 wave/SIMD (proven-bad latency regime). Here: 512 blocks x 8 waves =
// 2 blocks/CU x 16 waves = 4 waves/SIMD (proven regime). A = Gh/Gl planes
// from scan_p3; partials PO[2][4096][1024] summed by out_reduce.
// ---------------------------------------------------------------------------
__global__ __launch_bounds__(512, 4) void gemm1p(
    const ushort_t* __restrict__ Ghp, const ushort_t* __restrict__ Glp,
    const ushort_t* __restrict__ Bf, float* __restrict__ PO)
{
    __shared__ __align__(16) ushort_t AhS[2][128 * 32];   // 16 KiB
    __shared__ __align__(16) ushort_t AlS[2][128 * 32];   // 16 KiB
    __shared__ __align__(16) ushort_t BS[2][8 * 512];     // 16 KiB
    const int t = threadIdx.x;
    const int lin = blockIdx.x, xcd = lin & 7, s = lin >> 3;   // s in [0,64)
    const int ks = s >> 5;                        // split-K half
    const int r = s & 31;
    const int by = (xcd >> 1) * 8 + (r & 7);      // [0,32)
    const int bx = (xcd & 1) * 4 + (r >> 3);      // [0,8)
    const int m0 = by * 128, n0 = bx * 128;
    const int lane = t & 63, wave = t >> 6;
    const int wm = (wave & 3) * 32, wn = (wave >> 2) * 64;   // 4M x 2N
    const int m16 = lane & 15, q = lane >> 4;
    const int n16base = n0 >> 4;
    const int l16 = lane >> 2;
    const int csA = (lane & 3) ^ ((lane >> 3) & 3);
    const int kc0 = ks * 32;                      // 32 K-steps per half

    auto stageT = [&](int dbuf, int kc) {         // kc absolute
        const int r0 = wave * 16;
        const size_t ga = (size_t)(m0 + r0 + l16) * 2048 + kc * 32 + csA * 8;
        GLOAD16(Ghp + ga, &AhS[dbuf][r0 * 32]);
        GLOAD16(Glp + ga, &AlS[dbuf][r0 * 32]);
        const size_t gb = ((size_t)(n16base + wave) * 64 + kc) * 512 + lane * 8;
        GLOAD16(Bf + gb, &BS[dbuf][wave * 512]);
    };

    floatx4 acc[2][4];
    const floatx4 zz = {0.f, 0.f, 0.f, 0.f};
    #pragma unroll
    for (int i = 0; i < 2; ++i)
        #pragma unroll
        for (int j = 0; j < 4; ++j) acc[i][j] = zz;

    stageT(0, kc0);
    asm volatile("s_waitcnt vmcnt(0)" ::: "memory");
    __builtin_amdgcn_s_barrier();
    asm volatile("" ::: "memory");

    int cur = 0;
    for (int T = 0; T < 32; ++T) {
        const int nxt = cur ^ 1;
        if (T < 31) {
            stageT(nxt, kc0 + T + 1);
            asm volatile("s_waitcnt vmcnt(3)" ::: "memory");
        } else {
            asm volatile("s_waitcnt vmcnt(0)" ::: "memory");
        }
        __builtin_amdgcn_s_barrier();
        asm volatile("" ::: "memory");
        bf16x8 ah[2], al[2], bb[4];
        #pragma unroll
        for (int mi = 0; mi < 2; ++mi) {
            const int rr2 = wm + mi * 16 + m16;
            const int ch = q ^ ((m16 >> 1) & 3);
            ah[mi] = *(const bf16x8*)&AhS[cur][rr2 * 32 + ch * 8];
            al[mi] = *(const bf16x8*)&AlS[cur][rr2 * 32 + ch * 8];
        }
        #pragma unroll
        for (int j = 0; j < 4; ++j)
            bb[j] = *(const bf16x8*)&BS[cur][((wn >> 4) + j) * 512 + lane * 8];
        __builtin_amdgcn_s_setprio(1);
        #pragma unroll
        for (int mi = 0; mi < 2; ++mi)
            #pragma unroll
            for (int j = 0; j < 4; ++j) {
                acc[mi][j] = __builtin_amdgcn_mfma_f32_16x16x32_bf16(ah[mi], bb[j], acc[mi][j], 0, 0, 0);
                acc[mi][j] = __builtin_amdgcn_mfma_f32_16x16x32_bf16(al[mi], bb[j], acc[mi][j], 0, 0, 0);
            }
        __builtin_amdgcn_s_setprio(0);
        asm volatile("" ::: "memory");
        __builtin_amdgcn_s_barrier();
        asm volatile("" ::: "memory");
        cur = nxt;
    }

    float* Cp = PO + (size_t)ks * 4194304;
    #pragma unroll
    for (int i = 0; i < 2; ++i) {
        const int row_b = m0 + wm + i * 16 + q * 4;
        #pragma unroll
        for (int j = 0; j < 4; ++j) {
            const int col = n0 + wn + j * 16 + m16;
            #pragma unroll
            for (int rr = 0; rr < 4; ++rr) {
                const int row = row_b + rr;
                Cp[(size_t)row * 1024 + col] = acc[i][j][rr];
            }
        }
    }
}

// out = PO[0] + PO[1]  (4096x1024 fp32, float4)
__global__ __launch_bounds__(256) void out_reduce(
    const float* __restrict__ PO, float* __restrict__ out)
{
    const int i = (blockIdx.x * 256 + threadIdx.x) * 4;   // < 4194304
    float4 a = *(const float4*)&PO[i];
    float4 b = *(const float4*)&PO[4194304 + i];
    float4 rv;
    rv.x = a.x + b.x; rv.y = a.y + b.y; rv.z = a.z + b.z; rv.w = a.w + b.w;
    *(float4*)&out[i] = rv;
}

// ---------------------------------------------------------------------------
// Conv as MFMA GEMM — r7's verified best: 8-wave kc-half pipelined schedule
// + 8x8 XCD L2-locality tile map.
// ---------------------------------------------------------------------------
__global__ __launch_bounds__(512, 4) void conv2(
    const ushort_t* __restrict__ Xh, const ushort_t* __restrict__ Bf,
    const float* __restrict__ bias, uint_t* __restrict__ Upk)
{
    __shared__ __align__(16) ushort_t Asw[2][2][128 * 32];   // 32 KiB
    __shared__ __align__(16) ushort_t Bsw[2][2][8 * 512];    // 32 KiB
    const int t = threadIdx.x;
    const int lin = blockIdx.x, xcd = lin & 7, s = lin >> 3;   // s in [0,64)
    const int by  = (xcd >> 1) * 8 + (s & 7);    // r6-verified L2 tile map
    const int bxp = (xcd & 1) * 8 + (s >> 3);
    const int m0 = by * 128, n0 = bxp * 128;
    const int g1024 = (n0 >= 1024) ? 1024 : 0;
    const int lane = t & 63, wave = t >> 6;          // wave 0..7
    const int wm = (wave >> 2) * 64, wn = (wave & 3) * 32;
    const int m16 = lane & 15, q = lane >> 4;
    const int n16base = n0 >> 4;
    const int Xrow0 = (m0 >> 11) * 2051 + (m0 & 2047);   // b*2051 + l-base
    const int l16 = lane >> 2;                        // row within 16
    const int csA = (lane & 3) ^ ((lane >> 3) & 3);   // inverse-swizzled src chunk

    auto stageT = [&](int dbuf, int kcL, int Tn) {
        const int wtap = Tn >> 4;                     // conv tap, const per tile
        const int i0 = ((Tn << 6) & 1023) + kcL * 32; // k-col within tap group
        const int kc = Tn * 2 + kcL;
        {
            const int r0 = wave * 16;                 // wave-uniform row base
            const size_t gidx = (size_t)(Xrow0 + r0 + l16 + wtap) * 2048
                              + g1024 + i0 + csA * 8;
            GLOAD16(Xh + gidx, &Asw[dbuf][kcL][r0 * 32]);
        }
        {
            const size_t gidx = ((size_t)(n16base + wave) * 128 + kc) * 512 + lane * 8;
            GLOAD16(Bf + gidx, &Bsw[dbuf][kcL][wave * 512]);
        }
    };

    floatx4 acc[4][2];
    const floatx4 zz = {0.f, 0.f, 0.f, 0.f};
    #pragma unroll
    for (int i = 0; i < 4; ++i)
        #pragma unroll
        for (int j = 0; j < 2; ++j) acc[i][j] = zz;

    bf16x8 a0[4], b0[2], a1[4], b1[2];

    auto readA = [&](int dbuf, int kcL, bf16x8 (&ah)[4]) {
        #pragma unroll
        for (int mi = 0; mi < 4; ++mi) {
            const int rr2 = wm + mi * 16 + m16;
            const int ch = q ^ ((m16 >> 1) & 3);      // swizzled chunk
            ah[mi] = *(const bf16x8*)&Asw[dbuf][kcL][rr2 * 32 + ch * 8];
        }
    };
    auto readB = [&](int dbuf, int kcL, bf16x8 (&bb)[2]) {
        #pragma unroll
        for (int j = 0; j < 2; ++j)
            bb[j] = *(const bf16x8*)&Bsw[dbuf][kcL][((wn >> 4) + j) * 512 + lane * 8];
    };
    auto mfma8 = [&](bf16x8 (&ah)[4], bf16x8 (&bb)[2]) {
        __builtin_amdgcn_s_setprio(1);
        #pragma unroll
        for (int mi = 0; mi < 4; ++mi)
            #pragma unroll
            for (int j = 0; j < 2; ++j)
                acc[mi][j] = __builtin_amdgcn_mfma_f32_16x16x32_bf16(ah[mi], bb[j], acc[mi][j], 0, 0, 0);
        __builtin_amdgcn_s_setprio(0);
    };

    stageT(0, 0, 0);
    stageT(0, 1, 0);
    asm volatile("s_waitcnt vmcnt(2)" ::: "memory");
    __builtin_amdgcn_s_barrier();
    asm volatile("" ::: "memory");
    readA(0, 0, a0); readB(0, 0, b0);

    int cur = 0;
    for (int T = 0; T < 64; ++T) {
        const int nxt = cur ^ 1;
        if (T < 63) {
            stageT(nxt, 0, T + 1);                       // +2 (T+1,kc0)
            asm volatile("s_waitcnt vmcnt(2)" ::: "memory");   // (T,kc1) landed
        } else {
            asm volatile("s_waitcnt vmcnt(0)" ::: "memory");
        }
        __builtin_amdgcn_s_barrier();                    // (T,kc1) visible
        asm volatile("" ::: "memory");
        readA(cur, 1, a1); readB(cur, 1, b1);            // fly under next MFMA
        mfma8(a0, b0);                                   // consume (T,kc0)
        if (T < 63) stageT(nxt, 1, T + 1);               // +2 (T+1,kc1)
        mfma8(a1, b1);                                   // consume (T,kc1)
        asm volatile("" ::: "memory");
        if (T < 63) {
            asm volatile("s_waitcnt vmcnt(2)" ::: "memory");   // (T+1,kc0) landed
            __builtin_amdgcn_s_barrier();                // visible; all reads of
            asm volatile("" ::: "memory");               // buf[cur] consumed above
            readA(nxt, 0, a0); readB(nxt, 0, b0);        // fly under next iter
        }
        cur = nxt;
    }

    #pragma unroll
    for (int i = 0; i < 4; ++i) {
        const int row_b = m0 + wm + i * 16 + q * 4;
        #pragma unroll
        for (int j = 0; j < 2; ++j) {
            const int col = n0 + wn + j * 16 + m16;
            const float bz = bias[col];
            #pragma unroll
            for (int rr = 0; rr < 4; ++rr) {
                const int row = row_b + rr;
                const float v = silu_f(acc[i][j][rr] + bz);
                Upk[(size_t)row * 2048 + col] = packhl(v);
            }
        }
    }
}

// Sum the 4 split-K partials of dbc.
__global__ __launch_bounds__(256) void dbc_reduce(
    const float* __restrict__ DBCP, float* __restrict__ DBC)
{
    const int i = blockIdx.x * 256 + threadIdx.x;   // < 393216
    DBC[i] = (DBCP[i] + DBCP[393216 + i]) + (DBCP[786432 + i] + DBCP[1179648 + i]);
}

// ---------------------------------------------------------------------------
// delta[p,d] = clip(softplus(dbc[p,0:64] @ W_dt[:,d] + b_dt[d]), 1e-3, 1e-1)
// ---------------------------------------------------------------------------
__global__ __launch_bounds__(256) void delta_kernel(
    const float* __restrict__ DBC, const float* __restrict__ W_dt,
    const float* __restrict__ b_dt, float* __restrict__ DELTA)
{
    const int n  = blockIdx.x * 256 + threadIdx.x;
    const int p0 = blockIdx.y * 16;
    const int t  = threadIdx.x;
    __shared__ float dt_s[16][64];
    #pragma unroll
    for (int j = 0; j < 4; ++j) {
        const int lin = j * 256 + t;
        const int r = lin >> 6, k = lin & 63;
        dt_s[r][k] = DBC[(size_t)(p0 + r) * 96 + k];
    }
    __syncthreads();
    float acc[16];
    const float bz = b_dt[n];
    #pragma unroll
    for (int r = 0; r < 16; ++r) acc[r] = bz;
    for (int k = 0; k < 64; ++k) {
        const float wv = W_dt[(size_t)k * 2048 + n];
        #pragma unroll
        for (int r = 0; r < 16; ++r) acc[r] += dt_s[r][k] * wv;
    }
    #pragma unroll
    for (int r = 0; r < 16; ++r) {
        float a = acc[r];
        float sp = (a > 20.f) ? a : log1pf(expf(a));
        sp = fminf(fmaxf(sp, 0.001f), 0.1f);
        DELTA[(size_t)(p0 + r) * 2048 + n] = sp;
    }
}

// ---------------------------------------------------------------------------
// Chunked scan (64 chunks of 32). HEND/HINIT [c][b][d][16n]; SD[c][b][d].
// ---------------------------------------------------------------------------
__global__ __launch_bounds__(256) void scan_p1(
    const float* __restrict__ DELTA, const uint_t* __restrict__ Upk,
    const float* __restrict__ DBC, const float* __restrict__ A_log,
    float* __restrict__ HEND, float* __restrict__ SD)
{
    const int t = threadIdx.x;
    const int d = blockIdx.x * 256 + t;
    const int c = blockIdx.y;
    const int b = blockIdx.z;
    const int p0 = b * 2048 + c * 32;
    __shared__ float Bs[32][16];
    for (int lin = t; lin < 512; lin += 256) {
        const int s = lin >> 4, n = lin & 15;
        Bs[s][n] = DBC[(size_t)(p0 + s) * 96 + 64 + n];
    }
    __syncthreads();
    float Af[16];
    *(float4*)&Af[0]  = *(const float4*)&A_log[(size_t)d * 16 + 0];
    *(float4*)&Af[4]  = *(const float4*)&A_log[(size_t)d * 16 + 4];
    *(float4*)&Af[8]  = *(const float4*)&A_log[(size_t)d * 16 + 8];
    *(float4*)&Af[12] = *(const float4*)&A_log[(size_t)d * 16 + 12];
    #pragma unroll
    for (int n = 0; n < 16; ++n) Af[n] = -__expf(Af[n]);

    float h[16] = {};
    float sd = 0.f;
    for (int s = 0; s < 32; ++s) {
        const size_t ix = (size_t)(p0 + s) * 2048 + d;
        const float dv = DELTA[ix];
        const float uv = unpack_sum(Upk[ix]);
        const float du = dv * uv;
        sd += dv;
        #pragma unroll
        for (int n = 0; n < 16; ++n)
            h[n] = __expf(dv * Af[n]) * h[n] + du * Bs[s][n];
    }
    const size_t hb = (((size_t)c * 2 + b) * 2048 + d) * 16;
    *(float4*)&HEND[hb + 0]  = *(float4*)&h[0];
    *(float4*)&HEND[hb + 4]  = *(float4*)&h[4];
    *(float4*)&HEND[hb + 8]  = *(float4*)&h[8];
    *(float4*)&HEND[hb + 12] = *(float4*)&h[12];
    SD[((size_t)c * 2 + b) * 2048 + d] = sd;
}

__global__ __launch_bounds__(256) void scan_p2(
    const float* __restrict__ HEND, const float* __restrict__ SD,
    const float* __restrict__ A_log, float* __restrict__ HINIT)
{
    const int g = blockIdx.x * 256 + threadIdx.x;   // < 65536
    const int n = g & 15, d = (g >> 4) & 2047, b = (g >> 15) & 1;
    const float Af = -__expf(A_log[(size_t)d * 16 + n]);
    float h = 0.f;
    #pragma unroll 8
    for (int c = 0; c < 64; ++c) {
        const size_t cb = (size_t)c * 2 + b;
        const size_t idx = (cb * 2048 + d) * 16 + n;
        HINIT[idx] = h;
        h = __expf(Af * SD[cb * 2048 + d]) * h + HEND[idx];
    }
}

// Pass 3: re-scan from h_init, y, gate; emit G as Gh/Gl bf16 planes.
__global__ __launch_bounds__(256) void scan_p3(
    const float* __restrict__ DELTA, const uint_t* __restrict__ Upk,
    const float* __restrict__ DBC, const float* __restrict__ RES,
    const float* __restrict__ A_log, const float* __restrict__ Dp,
    const float* __restrict__ HINIT,
    ushort_t* __restrict__ Gh, ushort_t* __restrict__ Gl)
{
    const int t = threadIdx.x;
    const int d = blockIdx.x * 256 + t;
    const int c = blockIdx.y;
    const int b = blockIdx.z;
    const int p0 = b * 2048 + c * 32;
    __shared__ float Bs[32][16];
    __shared__ float Cs[32][16];
    for (int lin = t; lin < 512; lin += 256) {
        const int s = lin >> 4, n = lin & 15;
        Bs[s][n] = DBC[(size_t)(p0 + s) * 96 + 64 + n];
        Cs[s][n] = DBC[(size_t)(p0 + s) * 96 + 80 + n];
    }
    __syncthreads();
    float Af[16];
    *(float4*)&Af[0]  = *(const float4*)&A_log[(size_t)d * 16 + 0];
    *(float4*)&Af[4]  = *(const float4*)&A_log[(size_t)d * 16 + 4];
    *(float4*)&Af[8]  = *(const float4*)&A_log[(size_t)d * 16 + 8];
    *(float4*)&Af[12] = *(const float4*)&A_log[(size_t)d * 16 + 12];
    #pragma unroll
    for (int n = 0; n < 16; ++n) Af[n] = -__expf(Af[n]);

    const size_t hb = (((size_t)c * 2 + b) * 2048 + d) * 16;
    float h[16];
    *(float4*)&h[0]  = *(const float4*)&HINIT[hb + 0];
    *(float4*)&h[4]  = *(const float4*)&HINIT[hb + 4];
    *(float4*)&h[8]  = *(const float4*)&HINIT[hb + 8];
    *(float4*)&h[12] = *(const float4*)&HINIT[hb + 12];
    const float Dd = Dp[d];

    for (int s = 0; s < 32; ++s) {
        const int p = p0 + s;
        const size_t ix = (size_t)p * 2048 + d;
        const float dv = DELTA[ix];
        const float uv = unpack_sum(Upk[ix]);
        const float du = dv * uv;
        float y = 0.f;
        #pragma unroll
        for (int n = 0; n < 16; ++n) {
            h[n] = __expf(dv * Af[n]) * h[n] + du * Bs[s][n];
            y += h[n] * Cs[s][n];
        }
        const float resv = RES[ix];
        const float gv = (y + uv * Dd) * silu_f(resv);
        const unsigned short hh = f2bf(gv);
        Gh[ix] = hh;
        Gl[ix] = f2bf(gv - bf2f(hh));
    }
}

// ---------------------------------------------------------------------------
extern "C" void kernel_launch(void* const* d_in, const int* in_sizes, int n_in,
                              void* d_out, int out_size, void* d_ws, size_t ws_size,
                              hipStream_t stream) {
    const float* x      = (const float*)d_in[0];
    const float* W_in   = (const float*)d_in[1];
    const float* conv_k = (const float*)d_in[2];
    const float* conv_b = (const float*)d_in[3];
    const float* W_x    = (const float*)d_in[4];
    const float* W_dt   = (const float*)d_in[5];
    const float* b_dt   = (const float*)d_in[6];
    const float* A_log  = (const float*)d_in[7];
    const float* Dv     = (const float*)d_in[8];
    const float* W_out  = (const float*)d_in[9];
    float* out = (float*)d_out;

    char* base = (char*)d_ws;
    float*    RES      = (float*)(base);                  // 33,554,432
    uint_t*   Upk      = (uint_t*)(base + 33554432);      // 33,554,432
    float*    DELTA    = (float*)(base + 67108864);       // 33,554,432
    float*    PO       = (float*)(base + 67108864);       // alias over DELTA (dead after scan_p3)
    ushort_t* XSP_h    = (ushort_t*)(base + 100663296);   // 16,801,792 (2 x 2051 x 2048)
    float*    HEND     = (float*)(base + 100663296);      // alias over XSP (dead after conv2)
    ushort_t* xh       = (ushort_t*)(base + 117465088);   //  8,388,608 (x hi plane)
    ushort_t* xl       = (ushort_t*)(base + 125853696);   //  8,388,608 (x lo plane)
    ushort_t* convkF   = (ushort_t*)(base + 134242304);   // 16,777,216
    ushort_t* Gh       = (ushort_t*)(base + 117465088);   // alias over xh+xl (dead)
    ushort_t* Gl       = (ushort_t*)(base + 134242304);   // alias over convkF (dead)
    ushort_t* WinF     = (ushort_t*)(base + 151019520);   //  8,388,608
    ushort_t* WoutF    = (ushort_t*)(base + 159408128);   //  4,194,304
    ushort_t* WxF      = (ushort_t*)(base + 163602432);   //    524,288
    float*    DBCP     = (float*)(base + 164126720);      //  6,291,456
    float*    DBC      = (float*)(base + 170418176);      //  1,572,864
    float*    SD       = (float*)(base + 171991040);      //  1,048,576
    float*    HINIT    = (float*)(base + 173039616);      // 16,777,216

    // 0) all prep in one launch (x -> xh/xl split planes)
    prep_all<<<19504, 256, 0, stream>>>(x, W_in, conv_k, W_out, W_x,
                                        xh, xl, WinF, convkF, WoutF, WxF, XSP_h);
    // 1) xz: xs -> XSP bf16 hi (+pad), res -> RES fp32 (4Mx2N wave grid)
    gemm0p<<<1024, 512, 0, stream>>>(xh, xl, WinF, RES, XSP_h);
    // 2) u = silu(conv + b) -> Upk (r7 schedule + XCD L2 tile map)
    conv2<<<512, 512, 0, stream>>>(XSP_h, convkF, conv_b, Upk);
    // 3) dbc = U @ W_x, split-K x4 + reduce
    gemm2<2><<<dim3(4, 32), 256, 0, stream>>>(Upk, WxF, 2048, DBCP, nullptr);
    dbc_reduce<<<1536, 256, 0, stream>>>(DBCP, DBC);
    // 4) delta
    delta_kernel<<<dim3(8, 256), 256, 0, stream>>>(DBC, W_dt, b_dt, DELTA);
    // 5) chunked scan (p3 emits Gh/Gl planes)
    scan_p1<<<dim3(8, 64, 2), 256, 0, stream>>>(DELTA, Upk, DBC, A_log, HEND, SD);
    scan_p2<<<256, 256, 0, stream>>>(HEND, SD, A_log, HINIT);
    scan_p3<<<dim3(8, 64, 2), 256, 0, stream>>>(DELTA, Upk, DBC, RES, A_log, Dv,
                                                HINIT, Gh, Gl);
    // 6) out = G @ W_out (pipelined, split-K x2 + reduce)
    gemm1p<<<512, 512, 0, stream>>>(Gh, Gl, WoutF, PO);
    out_reduce<<<4096, 256, 0, stream>>>(PO, out);
}